// Round 1
// baseline (791.476 us; speedup 1.0000x reference)
//
#include <hip/hip_runtime.h>
#include <math.h>

// Problem constants (ViT-Base): B=4, S=1024, D=768, H=12, HD=64
constexpr int S_ = 1024;
constexpr int D_ = 768;
constexpr float SCALE = 0.125f;               // 1/sqrt(64)
constexpr long long MQN_ = 4096LL * 768;      // B*S*D = 3145728

// ---------------------------------------------------------------------------
// GEMM 1: mixed_q = X@Wq+bq (written twice to d_out), mixed_v = X@Wv+bv (ws)
// Tile 128x64, BK=32, 256 threads, each thread 8x4. grid (32, 24)
// ---------------------------------------------------------------------------
__global__ __launch_bounds__(256)
void k_gemm_qv(const float* __restrict__ X,
               const float* __restrict__ Wq, const float* __restrict__ bq,
               const float* __restrict__ Wv, const float* __restrict__ bv,
               float* __restrict__ mq1, float* __restrict__ mq2,
               float* __restrict__ mv)
{
    __shared__ float Xs[128][33];   // stride 33: scalar reads conflict-free
    __shared__ float Ws[32][64];    // float4 reads, 2-way (free)
    const int m0  = blockIdx.x * 128;
    const int n0g = blockIdx.y * 64;          // 0..1535 (virtual concat Q|V)
    const bool isQ = (n0g < 768);
    const float* __restrict__ W    = isQ ? Wq : Wv;
    const float* __restrict__ bias = isQ ? bq : bv;
    const int n0 = isQ ? n0g : (n0g - 768);
    const int tid = threadIdx.x;
    const int ty  = tid >> 4;
    const int tx4 = (tid & 15) << 2;

    float acc[8][4];
    #pragma unroll
    for (int i = 0; i < 8; ++i)
        #pragma unroll
        for (int j = 0; j < 4; ++j) acc[i][j] = 0.f;

    for (int k0 = 0; k0 < 768; k0 += 32) {
        #pragma unroll
        for (int it = 0; it < 4; ++it) {
            const int idx = tid + it * 256;
            const int row = idx >> 3;
            const int kc  = (idx & 7) << 2;
            const float4 v = *reinterpret_cast<const float4*>(
                &X[(size_t)(m0 + row) * 768 + k0 + kc]);
            Xs[row][kc + 0] = v.x; Xs[row][kc + 1] = v.y;
            Xs[row][kc + 2] = v.z; Xs[row][kc + 3] = v.w;
        }
        #pragma unroll
        for (int it = 0; it < 2; ++it) {
            const int idx = tid + it * 256;
            const int row = idx >> 4;
            const int nc  = (idx & 15) << 2;
            const float4 v = *reinterpret_cast<const float4*>(
                &W[(size_t)(k0 + row) * 768 + n0 + nc]);
            *reinterpret_cast<float4*>(&Ws[row][nc]) = v;
        }
        __syncthreads();
        #pragma unroll 4
        for (int kk = 0; kk < 32; ++kk) {
            float xv[8];
            #pragma unroll
            for (int i = 0; i < 8; ++i) xv[i] = Xs[ty + 16 * i][kk];
            const float4 wv = *reinterpret_cast<const float4*>(&Ws[kk][tx4]);
            const float wb[4] = { wv.x, wv.y, wv.z, wv.w };
            #pragma unroll
            for (int i = 0; i < 8; ++i)
                #pragma unroll
                for (int j = 0; j < 4; ++j)
                    acc[i][j] = fmaf(xv[i], wb[j], acc[i][j]);
        }
        __syncthreads();
    }
    const float4 b4 = *reinterpret_cast<const float4*>(&bias[n0 + tx4]);
    const float bb[4] = { b4.x, b4.y, b4.z, b4.w };
    #pragma unroll
    for (int i = 0; i < 8; ++i) {
        const int m = m0 + ty + 16 * i;
        float4 o;
        o.x = acc[i][0] + bb[0]; o.y = acc[i][1] + bb[1];
        o.z = acc[i][2] + bb[2]; o.w = acc[i][3] + bb[3];
        const size_t off = (size_t)m * 768 + n0 + tx4;
        if (isQ) {
            *reinterpret_cast<float4*>(&mq1[off]) = o;
            *reinterpret_cast<float4*>(&mq2[off]) = o;
        } else {
            *reinterpret_cast<float4*>(&mv[off]) = o;
        }
    }
}

// ---------------------------------------------------------------------------
// GEMM 2: out = ctx@Wo + bo. Same structure, grid (32, 12)
// ---------------------------------------------------------------------------
__global__ __launch_bounds__(256)
void k_gemm_one(const float* __restrict__ X, const float* __restrict__ W,
                const float* __restrict__ bias, float* __restrict__ out)
{
    __shared__ float Xs[128][33];
    __shared__ float Ws[32][64];
    const int m0 = blockIdx.x * 128;
    const int n0 = blockIdx.y * 64;
    const int tid = threadIdx.x;
    const int ty  = tid >> 4;
    const int tx4 = (tid & 15) << 2;

    float acc[8][4];
    #pragma unroll
    for (int i = 0; i < 8; ++i)
        #pragma unroll
        for (int j = 0; j < 4; ++j) acc[i][j] = 0.f;

    for (int k0 = 0; k0 < 768; k0 += 32) {
        #pragma unroll
        for (int it = 0; it < 4; ++it) {
            const int idx = tid + it * 256;
            const int row = idx >> 3;
            const int kc  = (idx & 7) << 2;
            const float4 v = *reinterpret_cast<const float4*>(
                &X[(size_t)(m0 + row) * 768 + k0 + kc]);
            Xs[row][kc + 0] = v.x; Xs[row][kc + 1] = v.y;
            Xs[row][kc + 2] = v.z; Xs[row][kc + 3] = v.w;
        }
        #pragma unroll
        for (int it = 0; it < 2; ++it) {
            const int idx = tid + it * 256;
            const int row = idx >> 4;
            const int nc  = (idx & 15) << 2;
            const float4 v = *reinterpret_cast<const float4*>(
                &W[(size_t)(k0 + row) * 768 + n0 + nc]);
            *reinterpret_cast<float4*>(&Ws[row][nc]) = v;
        }
        __syncthreads();
        #pragma unroll 4
        for (int kk = 0; kk < 32; ++kk) {
            float xv[8];
            #pragma unroll
            for (int i = 0; i < 8; ++i) xv[i] = Xs[ty + 16 * i][kk];
            const float4 wv = *reinterpret_cast<const float4*>(&Ws[kk][tx4]);
            const float wb[4] = { wv.x, wv.y, wv.z, wv.w };
            #pragma unroll
            for (int i = 0; i < 8; ++i)
                #pragma unroll
                for (int j = 0; j < 4; ++j)
                    acc[i][j] = fmaf(xv[i], wb[j], acc[i][j]);
        }
        __syncthreads();
    }
    const float4 b4 = *reinterpret_cast<const float4*>(&bias[n0 + tx4]);
    const float bb[4] = { b4.x, b4.y, b4.z, b4.w };
    #pragma unroll
    for (int i = 0; i < 8; ++i) {
        const int m = m0 + ty + 16 * i;
        float4 o;
        o.x = acc[i][0] + bb[0]; o.y = acc[i][1] + bb[1];
        o.z = acc[i][2] + bb[2]; o.w = acc[i][3] + bb[3];
        *reinterpret_cast<float4*>(&out[(size_t)m * 768 + n0 + tx4]) = o;
    }
}

// ---------------------------------------------------------------------------
// Column norms along sequence: inv_n[bh*64+d] = 1/max(||v[:,d]||, 1e-12)
// ---------------------------------------------------------------------------
__global__ __launch_bounds__(256)
void k_colnorm(const float* __restrict__ mv, float* __restrict__ inv_n)
{
    const int bh = blockIdx.x;                  // 0..47
    const int b = bh / 12, h = bh % 12;
    const int tid = threadIdx.x;
    const int d = tid & 63, chunk = tid >> 6;   // 4 chunks x 256 s
    const float* base = mv + (size_t)b * S_ * 768 + h * 64 + d;
    float p = 0.f;
    for (int s = chunk * 256; s < chunk * 256 + 256; ++s) {
        const float v = base[(size_t)s * 768];
        p = fmaf(v, v, p);
    }
    __shared__ float red[4][64];
    red[chunk][d] = p;
    __syncthreads();
    if (tid < 64) {
        const float sum = red[0][tid] + red[1][tid] + red[2][tid] + red[3][tid];
        const float n = fmaxf(sqrtf(sum), 1e-12f);
        inv_n[bh * 64 + tid] = 1.f / n;
    }
}

// ---------------------------------------------------------------------------
// Pass 1: per (b,h, 64-row s-tile): row max m_s and R'_s = sum exp(sc - m_s)
// grid (16, 48), 256 threads, thread computes 4x4 of each 64x64 score tile
// ---------------------------------------------------------------------------
__global__ __launch_bounds__(256)
void k_pass1(const float* __restrict__ q, float* __restrict__ mrow,
             float* __restrict__ rrow)
{
    const int st = blockIdx.x, bh = blockIdx.y;
    const int b = bh / 12, h = bh % 12;
    const int s0 = st * 64;
    const int tid = threadIdx.x;
    const int ty  = tid >> 4;
    const int tx4 = (tid & 15) << 2;
    __shared__ float Qs[64][65];   // odd stride: scalar reads conflict-free
    __shared__ float Qt[64][65];
    const float* qbase = q + (size_t)b * S_ * 768 + h * 64;

    #pragma unroll
    for (int it = 0; it < 4; ++it) {
        const int idx = tid + it * 256;
        const int row = idx >> 4;
        const int dc  = (idx & 15) << 2;
        const float4 v = *reinterpret_cast<const float4*>(
            &qbase[(size_t)(s0 + row) * 768 + dc]);
        Qs[row][dc + 0] = v.x; Qs[row][dc + 1] = v.y;
        Qs[row][dc + 2] = v.z; Qs[row][dc + 3] = v.w;
    }
    float m_i[4], r_i[4];
    #pragma unroll
    for (int i = 0; i < 4; ++i) { m_i[i] = -1e30f; r_i[i] = 0.f; }

    for (int tt = 0; tt < 16; ++tt) {
        __syncthreads();
        #pragma unroll
        for (int it = 0; it < 4; ++it) {
            const int idx = tid + it * 256;
            const int row = idx >> 4;
            const int dc  = (idx & 15) << 2;
            const float4 v = *reinterpret_cast<const float4*>(
                &qbase[(size_t)(tt * 64 + row) * 768 + dc]);
            Qt[row][dc + 0] = v.x; Qt[row][dc + 1] = v.y;
            Qt[row][dc + 2] = v.z; Qt[row][dc + 3] = v.w;
        }
        __syncthreads();
        float sc[4][4];
        #pragma unroll
        for (int i = 0; i < 4; ++i)
            #pragma unroll
            for (int j = 0; j < 4; ++j) sc[i][j] = 0.f;
        #pragma unroll 8
        for (int kk = 0; kk < 64; ++kk) {
            float av[4], bv_[4];
            av[0] = Qs[ty][kk];      av[1] = Qs[ty + 16][kk];
            av[2] = Qs[ty + 32][kk]; av[3] = Qs[ty + 48][kk];
            bv_[0] = Qt[tx4 + 0][kk]; bv_[1] = Qt[tx4 + 1][kk];
            bv_[2] = Qt[tx4 + 2][kk]; bv_[3] = Qt[tx4 + 3][kk];
            #pragma unroll
            for (int i = 0; i < 4; ++i)
                #pragma unroll
                for (int j = 0; j < 4; ++j)
                    sc[i][j] = fmaf(av[i], bv_[j], sc[i][j]);
        }
        #pragma unroll
        for (int i = 0; i < 4; ++i) {
            const float lm = fmaxf(fmaxf(sc[i][0], sc[i][1]),
                                   fmaxf(sc[i][2], sc[i][3])) * SCALE;
            const float nm = fmaxf(m_i[i], lm);
            float accr = 0.f;
            #pragma unroll
            for (int j = 0; j < 4; ++j) accr += __expf(sc[i][j] * SCALE - nm);
            r_i[i] = r_i[i] * __expf(m_i[i] - nm) + accr;
            m_i[i] = nm;
        }
    }
    __shared__ float Ms[64][17];
    __shared__ float Rs[64][17];
    const int tx = tid & 15;
    #pragma unroll
    for (int i = 0; i < 4; ++i) { Ms[ty + 16 * i][tx] = m_i[i]; Rs[ty + 16 * i][tx] = r_i[i]; }
    __syncthreads();
    if (tid < 64) {
        float m = -1e30f;
        for (int k = 0; k < 16; ++k) m = fmaxf(m, Ms[tid][k]);
        float r = 0.f;
        for (int k = 0; k < 16; ++k) r += Rs[tid][k] * __expf(Ms[tid][k] - m);
        mrow[(size_t)bh * S_ + s0 + tid] = m;
        rrow[(size_t)bh * S_ + s0 + tid] = r;
    }
}

// ---------------------------------------------------------------------------
// Per-head global max M and a_s = exp(M - m_s)/R'_s  (= 1/R_s w/ shift M)
// ---------------------------------------------------------------------------
__global__ __launch_bounds__(256)
void k_amax(const float* __restrict__ mrow, const float* __restrict__ rrow,
            float* __restrict__ Mh, float* __restrict__ a)
{
    const int bh = blockIdx.x;
    const int tid = threadIdx.x;
    float m = -1e30f;
    for (int s = tid; s < S_; s += 256) m = fmaxf(m, mrow[(size_t)bh * S_ + s]);
    __shared__ float red[256];
    red[tid] = m;
    __syncthreads();
    for (int w = 128; w >= 1; w >>= 1) {
        if (tid < w) red[tid] = fmaxf(red[tid], red[tid + w]);
        __syncthreads();
    }
    const float M = red[0];
    if (tid == 0) Mh[bh] = M;
    for (int s = tid; s < S_; s += 256)
        a[(size_t)bh * S_ + s] = __expf(M - mrow[(size_t)bh * S_ + s]) / rrow[(size_t)bh * S_ + s];
}

// ---------------------------------------------------------------------------
// Pass 2: ctx = probs@v (via ctx1=E@v, ctx2=(E*a_t)@v), g_s = sum E*a_t,
// plus tr partial sums. grid (16, 48). Qt/E share one LDS buffer.
// ---------------------------------------------------------------------------
__global__ __launch_bounds__(256)
void k_pass2(const float* __restrict__ q, const float* __restrict__ mv,
             const float* __restrict__ a, const float* __restrict__ Mh,
             const float* __restrict__ inv_n, float* __restrict__ ctx,
             float* __restrict__ t1p, float* __restrict__ t2p)
{
    const int st = blockIdx.x, bh = blockIdx.y;
    const int b = bh / 12, h = bh % 12;
    const int s0 = st * 64;
    const int tid = threadIdx.x;
    const int ty  = tid >> 4;
    const int tx  = tid & 15;
    const int tx4 = tx << 2;
    __shared__ float Qs[64][65];
    __shared__ float QtE[64][65];   // Qt during QK^T, then E tile
    __shared__ float Vt[64][68];    // stride 68: float4 reads aligned
    __shared__ float a_sh[64];
    __shared__ float Gred[64][16];
    const float* qbase = q  + (size_t)b * S_ * 768 + h * 64;
    const float* vbase = mv + (size_t)b * S_ * 768 + h * 64;
    const float Mhead = Mh[bh];

    #pragma unroll
    for (int it = 0; it < 4; ++it) {
        const int idx = tid + it * 256;
        const int row = idx >> 4;
        const int dc  = (idx & 15) << 2;
        const float4 v = *reinterpret_cast<const float4*>(
            &qbase[(size_t)(s0 + row) * 768 + dc]);
        Qs[row][dc + 0] = v.x; Qs[row][dc + 1] = v.y;
        Qs[row][dc + 2] = v.z; Qs[row][dc + 3] = v.w;
    }
    float ctx1[4][4], ctx2[4][4], g_loc[4];
    #pragma unroll
    for (int i = 0; i < 4; ++i) {
        g_loc[i] = 0.f;
        #pragma unroll
        for (int j = 0; j < 4; ++j) { ctx1[i][j] = 0.f; ctx2[i][j] = 0.f; }
    }

    for (int tt = 0; tt < 16; ++tt) {
        __syncthreads();   // previous iteration done with QtE/Vt
        #pragma unroll
        for (int it = 0; it < 4; ++it) {
            const int idx = tid + it * 256;
            const int row = idx >> 4;
            const int dc  = (idx & 15) << 2;
            const float4 v = *reinterpret_cast<const float4*>(
                &qbase[(size_t)(tt * 64 + row) * 768 + dc]);
            QtE[row][dc + 0] = v.x; QtE[row][dc + 1] = v.y;
            QtE[row][dc + 2] = v.z; QtE[row][dc + 3] = v.w;
            const float4 w = *reinterpret_cast<const float4*>(
                &vbase[(size_t)(tt * 64 + row) * 768 + dc]);
            *reinterpret_cast<float4*>(&Vt[row][dc]) = w;
        }
        if (tid < 64) a_sh[tid] = a[(size_t)bh * S_ + tt * 64 + tid];
        __syncthreads();
        // QK^T tile
        float sc[4][4];
        #pragma unroll
        for (int i = 0; i < 4; ++i)
            #pragma unroll
            for (int j = 0; j < 4; ++j) sc[i][j] = 0.f;
        #pragma unroll 8
        for (int kk = 0; kk < 64; ++kk) {
            float av[4], bv_[4];
            av[0] = Qs[ty][kk];      av[1] = Qs[ty + 16][kk];
            av[2] = Qs[ty + 32][kk]; av[3] = Qs[ty + 48][kk];
            bv_[0] = QtE[tx4 + 0][kk]; bv_[1] = QtE[tx4 + 1][kk];
            bv_[2] = QtE[tx4 + 2][kk]; bv_[3] = QtE[tx4 + 3][kk];
            #pragma unroll
            for (int i = 0; i < 4; ++i)
                #pragma unroll
                for (int j = 0; j < 4; ++j)
                    sc[i][j] = fmaf(av[i], bv_[j], sc[i][j]);
        }
        __syncthreads();   // everyone done reading QtE as Qt
        #pragma unroll
        for (int i = 0; i < 4; ++i)
            #pragma unroll
            for (int j = 0; j < 4; ++j) {
                const float e = __expf(sc[i][j] * SCALE - Mhead);
                sc[i][j] = e;
                g_loc[i] = fmaf(e, a_sh[tx4 + j], g_loc[i]);
            }
        #pragma unroll
        for (int i = 0; i < 4; ++i)
            #pragma unroll
            for (int j = 0; j < 4; ++j)
                QtE[ty + 16 * i][tx4 + j] = sc[i][j];   // E tile
        __syncthreads();
        // ctx accumulation: ctx1 += E@Vt, ctx2 += (E*a_t)@Vt
        #pragma unroll 8
        for (int kk = 0; kk < 64; ++kk) {
            const float avv = a_sh[kk];
            float ev[4];
            ev[0] = QtE[ty][kk];      ev[1] = QtE[ty + 16][kk];
            ev[2] = QtE[ty + 32][kk]; ev[3] = QtE[ty + 48][kk];
            const float4 vv = *reinterpret_cast<const float4*>(&Vt[kk][tx4]);
            const float w[4]  = { vv.x, vv.y, vv.z, vv.w };
            const float aw[4] = { avv * vv.x, avv * vv.y, avv * vv.z, avv * vv.w };
            #pragma unroll
            for (int i = 0; i < 4; ++i)
                #pragma unroll
                for (int j = 0; j < 4; ++j) {
                    ctx1[i][j] = fmaf(ev[i], w[j],  ctx1[i][j]);
                    ctx2[i][j] = fmaf(ev[i], aw[j], ctx2[i][j]);
                }
        }
    }
    // g reduction across the 16 column-threads per row
    #pragma unroll
    for (int i = 0; i < 4; ++i) Gred[ty + 16 * i][tx] = g_loc[i];
    __syncthreads();
    float t1 = 0.f, t2 = 0.f;
    const float4 nn = *reinterpret_cast<const float4*>(&inv_n[bh * 64 + tx4]);
    const float ns[4] = { nn.x, nn.y, nn.z, nn.w };
    #pragma unroll
    for (int i = 0; i < 4; ++i) {
        const int srow = ty + 16 * i;
        float g = 0.f;
        #pragma unroll
        for (int k = 0; k < 16; ++k) g += Gred[srow][k];
        const float dvec = 0.5f * (1.f + g);
        const float arow = a[(size_t)bh * S_ + s0 + srow];
        const size_t goff = (size_t)b * S_ * 768 + (size_t)(s0 + srow) * 768 + h * 64 + tx4;
        const float4 vv = *reinterpret_cast<const float4*>(&mv[goff]);
        const float vs[4] = { vv.x, vv.y, vv.z, vv.w };
        float cf[4];
        #pragma unroll
        for (int j = 0; j < 4; ++j) cf[j] = 0.5f * (arow * ctx1[i][j] + ctx2[i][j]);
        float4 co; co.x = cf[0]; co.y = cf[1]; co.z = cf[2]; co.w = cf[3];
        *reinterpret_cast<float4*>(&ctx[goff]) = co;
        #pragma unroll
        for (int j = 0; j < 4; ++j) {
            const float vn = vs[j] * ns[j];
            t1 = fmaf(vn, vn, t1);
            t2 += vs[j] * cf[j] * ns[j] * ns[j] / dvec;
        }
    }
    __shared__ float R1[256];
    __shared__ float R2[256];
    R1[tid] = t1; R2[tid] = t2;
    __syncthreads();
    for (int w = 128; w >= 1; w >>= 1) {
        if (tid < w) { R1[tid] += R1[tid + w]; R2[tid] += R2[tid + w]; }
        __syncthreads();
    }
    if (tid == 0) { t1p[bh * 16 + st] = R1[0]; t2p[bh * 16 + st] = R2[0]; }
}

// ---------------------------------------------------------------------------
// Orthogonality term: per head G = V^T V (64x64 Gram over S), sum (G-I)^2
// ---------------------------------------------------------------------------
__global__ __launch_bounds__(256)
void k_reg(const float* __restrict__ mv, const float* __restrict__ inv_n,
           float* __restrict__ regp)
{
    const int bh = blockIdx.x;
    const int b = bh / 12, h = bh % 12;
    const int tid = threadIdx.x;
    const int ty  = tid >> 4;
    const int tx4 = (tid & 15) << 2;
    __shared__ float Vt[64][68];
    const float* vbase = mv + (size_t)b * S_ * 768 + h * 64;
    float acc[4][4];
    #pragma unroll
    for (int i = 0; i < 4; ++i)
        #pragma unroll
        for (int j = 0; j < 4; ++j) acc[i][j] = 0.f;

    for (int ss = 0; ss < 16; ++ss) {
        __syncthreads();
        #pragma unroll
        for (int it = 0; it < 4; ++it) {
            const int idx = tid + it * 256;
            const int row = idx >> 4;
            const int dc  = (idx & 15) << 2;
            const float4 v = *reinterpret_cast<const float4*>(
                &vbase[(size_t)(ss * 64 + row) * 768 + dc]);
            *reinterpret_cast<float4*>(&Vt[row][dc]) = v;
        }
        __syncthreads();
        #pragma unroll 8
        for (int s = 0; s < 64; ++s) {
            float av[4];
            av[0] = Vt[s][ty];      av[1] = Vt[s][ty + 16];
            av[2] = Vt[s][ty + 32]; av[3] = Vt[s][ty + 48];
            const float4 bb = *reinterpret_cast<const float4*>(&Vt[s][tx4]);
            const float bw[4] = { bb.x, bb.y, bb.z, bb.w };
            #pragma unroll
            for (int i = 0; i < 4; ++i)
                #pragma unroll
                for (int j = 0; j < 4; ++j)
                    acc[i][j] = fmaf(av[i], bw[j], acc[i][j]);
        }
    }
    const float4 ne4 = *reinterpret_cast<const float4*>(&inv_n[bh * 64 + tx4]);
    const float ne[4] = { ne4.x, ne4.y, ne4.z, ne4.w };
    float part = 0.f;
    #pragma unroll
    for (int i = 0; i < 4; ++i) {
        const int drow = ty + 16 * i;
        const float nd = inv_n[bh * 64 + drow];
        #pragma unroll
        for (int j = 0; j < 4; ++j) {
            const float gv = acc[i][j] * nd * ne[j];
            const float diff = gv - ((drow == tx4 + j) ? 1.f : 0.f);
            part = fmaf(diff, diff, part);
        }
    }
    __shared__ float R[256];
    R[tid] = part;
    __syncthreads();
    for (int w = 128; w >= 1; w >>= 1) {
        if (tid < w) R[tid] += R[tid + w];
        __syncthreads();
    }
    if (tid == 0) regp[bh] = R[0];
}

// ---------------------------------------------------------------------------
// Final deterministic reduction: tr and regular_term scalars
// ---------------------------------------------------------------------------
__global__ __launch_bounds__(256)
void k_final(const float* __restrict__ t1p, const float* __restrict__ t2p,
             const float* __restrict__ regp, float* __restrict__ out_tr,
             float* __restrict__ out_reg)
{
    const int tid = threadIdx.x;
    float s1 = 0.f, s2 = 0.f, s3 = 0.f;
    for (int i = tid; i < 768; i += 256) { s1 += t1p[i]; s2 += t2p[i]; }
    if (tid < 48) s3 = regp[tid];
    __shared__ float R1[256];
    __shared__ float R2[256];
    __shared__ float R3[256];
    R1[tid] = s1; R2[tid] = s2; R3[tid] = s3;
    __syncthreads();
    for (int w = 128; w >= 1; w >>= 1) {
        if (tid < w) { R1[tid] += R1[tid + w]; R2[tid] += R2[tid + w]; R3[tid] += R3[tid + w]; }
        __syncthreads();
    }
    if (tid == 0) {
        *out_tr  = fabsf(R1[0] - R2[0]) / 3072.f;
        *out_reg = R3[0] / 3072.f;
    }
}

// ---------------------------------------------------------------------------
extern "C" void kernel_launch(void* const* d_in, const int* in_sizes, int n_in,
                              void* d_out, int out_size, void* d_ws, size_t ws_size,
                              hipStream_t stream)
{
    const float* X  = (const float*)d_in[0];
    const float* Wq = (const float*)d_in[1];
    const float* bq = (const float*)d_in[2];
    const float* Wv = (const float*)d_in[3];
    const float* bv = (const float*)d_in[4];
    const float* Wo = (const float*)d_in[5];
    const float* bo = (const float*)d_in[6];

    float* out = (float*)d_out;
    float* att = out;                         // [4096,768]
    float* tr  = out + 3145728;
    float* rg  = out + 3145729;
    float* mq1 = out + 3145730;               // mixed_q (output 3)
    float* mq2 = out + 6291458;               // mixed_q (output 4)

    float* ws   = (float*)d_ws;               // needs ~25.8 MB
    float* mv   = ws;                         // [4096,768]
    float* ctx  = ws + 3145728;               // [4096,768]
    float* mrow = ws + 6291456;               // [48,1024]
    float* rrow = ws + 6340608;               // [48,1024]
    float* aarr = ws + 6389760;               // [48,1024]
    float* Mh   = ws + 6438912;               // [48]
    float* invn = ws + 6438960;               // [48,64]
    float* t1p  = ws + 6442032;               // [768]
    float* t2p  = ws + 6442800;               // [768]
    float* regp = ws + 6443568;               // [48]

    if (ws_size < (size_t)6443616 * sizeof(float)) return;  // scratch too small

    k_gemm_qv <<<dim3(32, 24), 256, 0, stream>>>(X, Wq, bq, Wv, bv, mq1, mq2, mv);
    k_colnorm <<<48,           256, 0, stream>>>(mv, invn);
    k_pass1   <<<dim3(16, 48), 256, 0, stream>>>(mq1, mrow, rrow);
    k_amax    <<<48,           256, 0, stream>>>(mrow, rrow, Mh, aarr);
    k_pass2   <<<dim3(16, 48), 256, 0, stream>>>(mq1, mv, aarr, Mh, invn, ctx, t1p, t2p);
    k_reg     <<<48,           256, 0, stream>>>(mv, invn, regp);
    k_final   <<<1,            256, 0, stream>>>(t1p, t2p, regp, tr, rg);
    k_gemm_one<<<dim3(32, 12), 256, 0, stream>>>(ctx, Wo, bo, att);
}

// Round 2
// 415.484 us; speedup vs baseline: 1.9049x; 1.9049x over previous
//
#include <hip/hip_runtime.h>
#include <math.h>

// Problem constants (ViT-Base): B=4, S=1024, D=768, H=12, HD=64
constexpr float SCALE = 0.125f;               // 1/sqrt(64)

typedef __attribute__((ext_vector_type(8))) short bf8;            // 8 bf16 (4 VGPRs)
typedef __attribute__((ext_vector_type(8))) unsigned short u16x8;
typedef __attribute__((ext_vector_type(4))) float f32x4;

static __device__ __forceinline__ unsigned short f2bf(float f) {
    unsigned int u = __float_as_uint(f);
    u += 0x7fffu + ((u >> 16) & 1u);          // round-to-nearest-even
    return (unsigned short)(u >> 16);
}
static __device__ __forceinline__ float bf2f(unsigned short h) {
    return __uint_as_float(((unsigned int)h) << 16);
}
static __device__ __forceinline__ bf8 ld8(const unsigned short* p) {
    return *reinterpret_cast<const bf8*>(p);
}

// ---------------------------------------------------------------------------
// GEMM 1 (fp32 VALU): mq = X@Wq+bq -> d_out twice + bf16 qb; mv -> bf16 mvb
// ---------------------------------------------------------------------------
__global__ __launch_bounds__(256)
void k_gemm_qv(const float* __restrict__ X,
               const float* __restrict__ Wq, const float* __restrict__ bq,
               const float* __restrict__ Wv, const float* __restrict__ bv,
               float* __restrict__ mq1, float* __restrict__ mq2,
               unsigned short* __restrict__ qb, unsigned short* __restrict__ mvb)
{
    __shared__ float Xs[128][33];
    __shared__ float Ws[32][64];
    const int m0  = blockIdx.x * 128;
    const int n0g = blockIdx.y * 64;
    const bool isQ = (n0g < 768);
    const float* __restrict__ W    = isQ ? Wq : Wv;
    const float* __restrict__ bias = isQ ? bq : bv;
    const int n0 = isQ ? n0g : (n0g - 768);
    const int tid = threadIdx.x;
    const int ty  = tid >> 4;
    const int tx4 = (tid & 15) << 2;

    float acc[8][4];
    #pragma unroll
    for (int i = 0; i < 8; ++i)
        #pragma unroll
        for (int j = 0; j < 4; ++j) acc[i][j] = 0.f;

    for (int k0 = 0; k0 < 768; k0 += 32) {
        #pragma unroll
        for (int it = 0; it < 4; ++it) {
            const int idx = tid + it * 256;
            const int row = idx >> 3;
            const int kc  = (idx & 7) << 2;
            const float4 v = *reinterpret_cast<const float4*>(
                &X[(size_t)(m0 + row) * 768 + k0 + kc]);
            Xs[row][kc + 0] = v.x; Xs[row][kc + 1] = v.y;
            Xs[row][kc + 2] = v.z; Xs[row][kc + 3] = v.w;
        }
        #pragma unroll
        for (int it = 0; it < 2; ++it) {
            const int idx = tid + it * 256;
            const int row = idx >> 4;
            const int nc  = (idx & 15) << 2;
            const float4 v = *reinterpret_cast<const float4*>(
                &W[(size_t)(k0 + row) * 768 + n0 + nc]);
            *reinterpret_cast<float4*>(&Ws[row][nc]) = v;
        }
        __syncthreads();
        #pragma unroll 4
        for (int kk = 0; kk < 32; ++kk) {
            float xv[8];
            #pragma unroll
            for (int i = 0; i < 8; ++i) xv[i] = Xs[ty + 16 * i][kk];
            const float4 wv = *reinterpret_cast<const float4*>(&Ws[kk][tx4]);
            const float wb[4] = { wv.x, wv.y, wv.z, wv.w };
            #pragma unroll
            for (int i = 0; i < 8; ++i)
                #pragma unroll
                for (int j = 0; j < 4; ++j)
                    acc[i][j] = fmaf(xv[i], wb[j], acc[i][j]);
        }
        __syncthreads();
    }
    const float4 b4 = *reinterpret_cast<const float4*>(&bias[n0 + tx4]);
    const float bb[4] = { b4.x, b4.y, b4.z, b4.w };
    #pragma unroll
    for (int i = 0; i < 8; ++i) {
        const int m = m0 + ty + 16 * i;
        float4 o;
        o.x = acc[i][0] + bb[0]; o.y = acc[i][1] + bb[1];
        o.z = acc[i][2] + bb[2]; o.w = acc[i][3] + bb[3];
        const size_t off = (size_t)m * 768 + n0 + tx4;
        if (isQ) {
            *reinterpret_cast<float4*>(&mq1[off]) = o;
            *reinterpret_cast<float4*>(&mq2[off]) = o;
            ushort4 hq;
            hq.x = f2bf(o.x); hq.y = f2bf(o.y); hq.z = f2bf(o.z); hq.w = f2bf(o.w);
            *reinterpret_cast<ushort4*>(&qb[off]) = hq;
        } else {
            ushort4 hv;
            hv.x = f2bf(o.x); hv.y = f2bf(o.y); hv.z = f2bf(o.z); hv.w = f2bf(o.w);
            *reinterpret_cast<ushort4*>(&mvb[off]) = hv;
        }
    }
}

// ---------------------------------------------------------------------------
// GEMM 2 (fp32 VALU): out = ctx(bf16)@Wo + bo
// ---------------------------------------------------------------------------
__global__ __launch_bounds__(256)
void k_gemm_one(const unsigned short* __restrict__ Xb, const float* __restrict__ W,
                const float* __restrict__ bias, float* __restrict__ out)
{
    __shared__ float Xs[128][33];
    __shared__ float Ws[32][64];
    const int m0 = blockIdx.x * 128;
    const int n0 = blockIdx.y * 64;
    const int tid = threadIdx.x;
    const int ty  = tid >> 4;
    const int tx4 = (tid & 15) << 2;

    float acc[8][4];
    #pragma unroll
    for (int i = 0; i < 8; ++i)
        #pragma unroll
        for (int j = 0; j < 4; ++j) acc[i][j] = 0.f;

    for (int k0 = 0; k0 < 768; k0 += 32) {
        #pragma unroll
        for (int it = 0; it < 2; ++it) {
            const int idx = tid + it * 256;
            const int row = idx >> 2;            // 0..127
            const int kc  = (idx & 3) << 3;      // 0,8,16,24
            const u16x8 u = *reinterpret_cast<const u16x8*>(
                &Xb[(size_t)(m0 + row) * 768 + k0 + kc]);
            #pragma unroll
            for (int k = 0; k < 8; ++k) Xs[row][kc + k] = bf2f(u[k]);
        }
        #pragma unroll
        for (int it = 0; it < 2; ++it) {
            const int idx = tid + it * 256;
            const int row = idx >> 4;
            const int nc  = (idx & 15) << 2;
            const float4 v = *reinterpret_cast<const float4*>(
                &W[(size_t)(k0 + row) * 768 + n0 + nc]);
            *reinterpret_cast<float4*>(&Ws[row][nc]) = v;
        }
        __syncthreads();
        #pragma unroll 4
        for (int kk = 0; kk < 32; ++kk) {
            float xv[8];
            #pragma unroll
            for (int i = 0; i < 8; ++i) xv[i] = Xs[ty + 16 * i][kk];
            const float4 wv = *reinterpret_cast<const float4*>(&Ws[kk][tx4]);
            const float wb[4] = { wv.x, wv.y, wv.z, wv.w };
            #pragma unroll
            for (int i = 0; i < 8; ++i)
                #pragma unroll
                for (int j = 0; j < 4; ++j)
                    acc[i][j] = fmaf(xv[i], wb[j], acc[i][j]);
        }
        __syncthreads();
    }
    const float4 b4 = *reinterpret_cast<const float4*>(&bias[n0 + tx4]);
    const float bb[4] = { b4.x, b4.y, b4.z, b4.w };
    #pragma unroll
    for (int i = 0; i < 8; ++i) {
        const int m = m0 + ty + 16 * i;
        float4 o;
        o.x = acc[i][0] + bb[0]; o.y = acc[i][1] + bb[1];
        o.z = acc[i][2] + bb[2]; o.w = acc[i][3] + bb[3];
        *reinterpret_cast<float4*>(&out[(size_t)m * 768 + n0 + tx4]) = o;
    }
}

// ---------------------------------------------------------------------------
// Column norms along sequence + t1 = sum (v*inv)^2 per head
// ---------------------------------------------------------------------------
__global__ __launch_bounds__(256)
void k_colnorm(const unsigned short* __restrict__ mvb, float* __restrict__ inv_n,
               float* __restrict__ t1p)
{
    const int bh = blockIdx.x;
    const int b = bh / 12, h = bh % 12;
    const int tid = threadIdx.x;
    const int d = tid & 63, chunk = tid >> 6;
    const unsigned short* base = mvb + (size_t)b * 1024 * 768 + h * 64 + d;
    float p = 0.f;
    for (int s = chunk * 256; s < chunk * 256 + 256; ++s) {
        const float v = bf2f(base[(size_t)s * 768]);
        p = fmaf(v, v, p);
    }
    __shared__ float red[4][64];
    __shared__ float t1s[64];
    red[chunk][d] = p;
    __syncthreads();
    if (tid < 64) {
        const float sum = red[0][tid] + red[1][tid] + red[2][tid] + red[3][tid];
        const float n = fmaxf(sqrtf(sum), 1e-12f);
        const float iv = 1.f / n;
        inv_n[bh * 64 + tid] = iv;
        t1s[tid] = sum * iv * iv;
    }
    __syncthreads();
    if (tid == 0) {
        float t = 0.f;
        for (int k = 0; k < 64; ++k) t += t1s[k];
        t1p[bh] = t;
    }
}

// ---------------------------------------------------------------------------
// Transpose V per head: vT[bh][d (64)][t (1024)] bf16
// ---------------------------------------------------------------------------
__global__ __launch_bounds__(256)
void k_transpose(const unsigned short* __restrict__ mvb, unsigned short* __restrict__ vT)
{
    __shared__ unsigned short T[64 * 72];
    const int st = blockIdx.x, bh = blockIdx.y;
    const int b = bh / 12, h = bh % 12;
    const int s0 = st * 64;
    const int tid = threadIdx.x;
    const int r  = tid >> 2;
    const int c0 = (tid & 3) * 16;
    const unsigned short* src = mvb + (size_t)(b * 1024 + s0 + r) * 768 + h * 64 + c0;
    const u16x8 x0 = *reinterpret_cast<const u16x8*>(src);
    const u16x8 x1 = *reinterpret_cast<const u16x8*>(src + 8);
    *reinterpret_cast<u16x8*>(&T[r * 72 + c0])     = x0;
    *reinterpret_cast<u16x8*>(&T[r * 72 + c0 + 8]) = x1;
    __syncthreads();
    const int dd  = tid >> 2;
    const int sc0 = (tid & 3) * 16;
    u16x8 o0, o1;
    #pragma unroll
    for (int k = 0; k < 8; ++k) o0[k] = T[(sc0 + k) * 72 + dd];
    #pragma unroll
    for (int k = 0; k < 8; ++k) o1[k] = T[(sc0 + 8 + k) * 72 + dd];
    unsigned short* dst = vT + (size_t)bh * 65536 + (size_t)dd * 1024 + s0 + sc0;
    *reinterpret_cast<u16x8*>(dst)     = o0;
    *reinterpret_cast<u16x8*>(dst + 8) = o1;
}

// ---------------------------------------------------------------------------
// Pass 1 (MFMA): per-row running max m_s and R'_s = sum exp(sc - m_s)
// grid (16, 48), 4 waves; operands straight from global (L1-cached)
// ---------------------------------------------------------------------------
__global__ __launch_bounds__(256)
void k_pass1(const unsigned short* __restrict__ qb,
             float* __restrict__ mrow, float* __restrict__ rrow)
{
    const int st = blockIdx.x, bh = blockIdx.y;
    const int b = bh / 12, h = bh % 12;
    const int s0 = st * 64;
    const int tid = threadIdx.x;
    const int w = tid >> 6, lane = tid & 63, lm = lane & 15, lg = lane >> 4;
    const size_t qoff = (size_t)(b * 1024) * 768 + h * 64;
    const unsigned short* arow = qb + qoff + (size_t)(s0 + 16 * w + lm) * 768;
    const bf8 a0 = ld8(arow + 8 * lg);
    const bf8 a1 = ld8(arow + 32 + 8 * lg);
    const f32x4 z = {0.f, 0.f, 0.f, 0.f};
    float m_j[4], r_j[4];
    #pragma unroll
    for (int j = 0; j < 4; ++j) { m_j[j] = -1e30f; r_j[j] = 0.f; }

    for (int tt = 0; tt < 16; ++tt) {
        const int t0 = tt * 64;
        f32x4 accf[4];
        #pragma unroll
        for (int nf = 0; nf < 4; ++nf) {
            const unsigned short* brow = qb + qoff + (size_t)(t0 + 16 * nf + lm) * 768;
            const bf8 b0 = ld8(brow + 8 * lg);
            const bf8 b1 = ld8(brow + 32 + 8 * lg);
            f32x4 acc = __builtin_amdgcn_mfma_f32_16x16x32_bf16(a0, b0, z, 0, 0, 0);
            acc = __builtin_amdgcn_mfma_f32_16x16x32_bf16(a1, b1, acc, 0, 0, 0);
            accf[nf] = acc;
        }
        #pragma unroll
        for (int j = 0; j < 4; ++j) {
            const float v0 = accf[0][j] * SCALE, v1 = accf[1][j] * SCALE;
            const float v2 = accf[2][j] * SCALE, v3 = accf[3][j] * SCALE;
            const float lmx = fmaxf(fmaxf(v0, v1), fmaxf(v2, v3));
            const float nm = fmaxf(m_j[j], lmx);
            const float s = __expf(v0 - nm) + __expf(v1 - nm) +
                            __expf(v2 - nm) + __expf(v3 - nm);
            r_j[j] = r_j[j] * __expf(m_j[j] - nm) + s;
            m_j[j] = nm;
        }
    }
    #pragma unroll
    for (int j = 0; j < 4; ++j)
        #pragma unroll
        for (int k = 1; k < 16; k <<= 1) {
            const float om  = __shfl_xor(m_j[j], k);
            const float orr = __shfl_xor(r_j[j], k);
            const float nm = fmaxf(m_j[j], om);
            r_j[j] = r_j[j] * __expf(m_j[j] - nm) + orr * __expf(om - nm);
            m_j[j] = nm;
        }
    if (lm == 0) {
        #pragma unroll
        for (int j = 0; j < 4; ++j) {
            const int srow = s0 + 16 * w + 4 * lg + j;
            mrow[(size_t)bh * 1024 + srow] = m_j[j];
            rrow[(size_t)bh * 1024 + srow] = r_j[j];
        }
    }
}

// ---------------------------------------------------------------------------
// Per-head global max M and a_s = exp(M - m_s)/R'_s
// ---------------------------------------------------------------------------
__global__ __launch_bounds__(256)
void k_amax(const float* __restrict__ mrow, const float* __restrict__ rrow,
            float* __restrict__ Mh, float* __restrict__ a)
{
    const int bh = blockIdx.x;
    const int tid = threadIdx.x;
    float m = -1e30f;
    for (int s = tid; s < 1024; s += 256) m = fmaxf(m, mrow[(size_t)bh * 1024 + s]);
    __shared__ float red[256];
    red[tid] = m;
    __syncthreads();
    for (int w = 128; w >= 1; w >>= 1) {
        if (tid < w) red[tid] = fmaxf(red[tid], red[tid + w]);
        __syncthreads();
    }
    const float M = red[0];
    if (tid == 0) Mh[bh] = M;
    for (int s = tid; s < 1024; s += 256)
        a[(size_t)bh * 1024 + s] =
            __expf(M - mrow[(size_t)bh * 1024 + s]) / rrow[(size_t)bh * 1024 + s];
}

// ---------------------------------------------------------------------------
// Pass 2 (MFMA): E=exp(sc-M); ctx1=E@V, ctx2=E@(a.V); g=E@a; ctx + t2 partials
// grid (16, 48), 4 waves. LDS stride 72 elems (16B aligned, minimal aliasing)
// ---------------------------------------------------------------------------
__global__ __launch_bounds__(256)
void k_pass2(const unsigned short* __restrict__ qb,
             const unsigned short* __restrict__ vT,
             const unsigned short* __restrict__ mvb,
             const float* __restrict__ a, const float* __restrict__ Mh,
             const float* __restrict__ invn,
             unsigned short* __restrict__ ctxb,
             float* __restrict__ t2p)
{
    __shared__ unsigned short E_lds[64 * 72];
    __shared__ unsigned short Vt_lds[64 * 72];
    __shared__ unsigned short Va_lds[64 * 72];
    __shared__ float red[256];
    const int st = blockIdx.x, bh = blockIdx.y;
    const int b = bh / 12, h = bh % 12;
    const int s0 = st * 64;
    const int tid = threadIdx.x;
    const int w = tid >> 6, lane = tid & 63, lm = lane & 15, lg = lane >> 4;
    const float Mhead = Mh[bh];
    const size_t qoff = (size_t)(b * 1024) * 768 + h * 64;
    const unsigned short* arow_p = qb + qoff + (size_t)(s0 + 16 * w + lm) * 768;
    const bf8 qa0 = ld8(arow_p + 8 * lg);
    const bf8 qa1 = ld8(arow_p + 32 + 8 * lg);
    const int vrow = tid >> 2;          // d 0..63
    const int tcol = (tid & 3) * 16;    // t-offset within chunk
    const unsigned short* vTbase = vT + (size_t)bh * 65536 + (size_t)vrow * 1024;
    const float* abase = a + (size_t)bh * 1024;
    float inv2[4];
    #pragma unroll
    for (int nf = 0; nf < 4; ++nf) {
        const float iv = invn[bh * 64 + lm + 16 * nf];
        inv2[nf] = iv * iv;
    }
    const f32x4 z = {0.f, 0.f, 0.f, 0.f};
    f32x4 acc1[4], acc2[4];
    #pragma unroll
    for (int nf = 0; nf < 4; ++nf) { acc1[nf] = z; acc2[nf] = z; }
    float gpart[4] = {0.f, 0.f, 0.f, 0.f};

    for (int tt = 0; tt < 16; ++tt) {
        const int t0 = tt * 64;
        // early V/a loads (hide under QK^T)
        const u16x8 v0 = *reinterpret_cast<const u16x8*>(vTbase + t0 + tcol);
        const u16x8 v1 = *reinterpret_cast<const u16x8*>(vTbase + t0 + tcol + 8);
        const float4 af0 = *reinterpret_cast<const float4*>(abase + t0 + tcol);
        const float4 af1 = *reinterpret_cast<const float4*>(abase + t0 + tcol + 4);
        const float4 af2 = *reinterpret_cast<const float4*>(abase + t0 + tcol + 8);
        const float4 af3 = *reinterpret_cast<const float4*>(abase + t0 + tcol + 12);
        // QQ^T tile via MFMA (operands from global/L1)
        f32x4 ef[4];
        #pragma unroll
        for (int nf = 0; nf < 4; ++nf) {
            const unsigned short* brow = qb + qoff + (size_t)(t0 + 16 * nf + lm) * 768;
            const bf8 b0 = ld8(brow + 8 * lg);
            const bf8 b1 = ld8(brow + 32 + 8 * lg);
            f32x4 acc = __builtin_amdgcn_mfma_f32_16x16x32_bf16(qa0, b0, z, 0, 0, 0);
            acc = __builtin_amdgcn_mfma_f32_16x16x32_bf16(qa1, b1, acc, 0, 0, 0);
            ef[nf] = acc;
        }
        float e_val[4][4];
        #pragma unroll
        for (int nf = 0; nf < 4; ++nf) {
            const float ac = abase[t0 + 16 * nf + lm];
            #pragma unroll
            for (int j = 0; j < 4; ++j) {
                const float e = __expf(ef[nf][j] * SCALE - Mhead);
                e_val[nf][j] = e;
                gpart[j] = fmaf(e, ac, gpart[j]);
            }
        }
        __syncthreads();   // previous chunk's LDS consumers done
        #pragma unroll
        for (int nf = 0; nf < 4; ++nf)
            #pragma unroll
            for (int j = 0; j < 4; ++j)
                E_lds[(16 * w + 4 * lg + j) * 72 + lm + 16 * nf] = f2bf(e_val[nf][j]);
        *reinterpret_cast<u16x8*>(&Vt_lds[vrow * 72 + tcol])     = v0;
        *reinterpret_cast<u16x8*>(&Vt_lds[vrow * 72 + tcol + 8]) = v1;
        u16x8 w0, w1;
        w0[0] = f2bf(bf2f(v0[0]) * af0.x); w0[1] = f2bf(bf2f(v0[1]) * af0.y);
        w0[2] = f2bf(bf2f(v0[2]) * af0.z); w0[3] = f2bf(bf2f(v0[3]) * af0.w);
        w0[4] = f2bf(bf2f(v0[4]) * af1.x); w0[5] = f2bf(bf2f(v0[5]) * af1.y);
        w0[6] = f2bf(bf2f(v0[6]) * af1.z); w0[7] = f2bf(bf2f(v0[7]) * af1.w);
        w1[0] = f2bf(bf2f(v1[0]) * af2.x); w1[1] = f2bf(bf2f(v1[1]) * af2.y);
        w1[2] = f2bf(bf2f(v1[2]) * af2.z); w1[3] = f2bf(bf2f(v1[3]) * af2.w);
        w1[4] = f2bf(bf2f(v1[4]) * af3.x); w1[5] = f2bf(bf2f(v1[5]) * af3.y);
        w1[6] = f2bf(bf2f(v1[6]) * af3.z); w1[7] = f2bf(bf2f(v1[7]) * af3.w);
        *reinterpret_cast<u16x8*>(&Va_lds[vrow * 72 + tcol])     = w0;
        *reinterpret_cast<u16x8*>(&Va_lds[vrow * 72 + tcol + 8]) = w1;
        __syncthreads();   // E/V ready
        #pragma unroll
        for (int ks = 0; ks < 2; ++ks) {
            const bf8 ae = *reinterpret_cast<const bf8*>(
                &E_lds[(16 * w + lm) * 72 + 32 * ks + 8 * lg]);
            #pragma unroll
            for (int nf = 0; nf < 4; ++nf) {
                const bf8 bv = *reinterpret_cast<const bf8*>(
                    &Vt_lds[(lm + 16 * nf) * 72 + 32 * ks + 8 * lg]);
                const bf8 ba = *reinterpret_cast<const bf8*>(
                    &Va_lds[(lm + 16 * nf) * 72 + 32 * ks + 8 * lg]);
                acc1[nf] = __builtin_amdgcn_mfma_f32_16x16x32_bf16(ae, bv, acc1[nf], 0, 0, 0);
                acc2[nf] = __builtin_amdgcn_mfma_f32_16x16x32_bf16(ae, ba, acc2[nf], 0, 0, 0);
            }
        }
    }
    // full row-sum g across the 16 column-lanes
    #pragma unroll
    for (int j = 0; j < 4; ++j)
        #pragma unroll
        for (int k = 1; k < 16; k <<= 1)
            gpart[j] += __shfl_xor(gpart[j], k);

    float t2 = 0.f;
    #pragma unroll
    for (int j = 0; j < 4; ++j) {
        const int srow = s0 + 16 * w + 4 * lg + j;
        const float arow = abase[srow];
        const float rdv = 1.f / (0.5f * (1.f + gpart[j]));
        const size_t rowoff = (size_t)(b * 1024 + srow) * 768 + h * 64;
        #pragma unroll
        for (int nf = 0; nf < 4; ++nf) {
            const int d = lm + 16 * nf;
            const float cf = 0.5f * (arow * acc1[nf][j] + acc2[nf][j]);
            ctxb[rowoff + d] = f2bf(cf);
            const float vv = bf2f(mvb[rowoff + d]);
            t2 = fmaf(vv * cf, inv2[nf] * rdv, t2);
        }
    }
    red[tid] = t2;
    __syncthreads();
    for (int k = 128; k >= 1; k >>= 1) {
        if (tid < k) red[tid] += red[tid + k];
        __syncthreads();
    }
    if (tid == 0) t2p[bh * 16 + st] = red[0];
}

// ---------------------------------------------------------------------------
// Orthogonality term via MFMA Gram from vT: sum (VtV - I)^2 per head
// ---------------------------------------------------------------------------
__global__ __launch_bounds__(256)
void k_reg(const unsigned short* __restrict__ vT, const float* __restrict__ invn,
           float* __restrict__ regp)
{
    const int bh = blockIdx.x;
    const int tid = threadIdx.x;
    const int w = tid >> 6, lane = tid & 63, lm = lane & 15, lg = lane >> 4;
    const unsigned short* base = vT + (size_t)bh * 65536;
    const unsigned short* arowp = base + (size_t)(16 * w + lm) * 1024;
    const f32x4 z = {0.f, 0.f, 0.f, 0.f};
    f32x4 acc[4];
    #pragma unroll
    for (int nf = 0; nf < 4; ++nf) acc[nf] = z;
    for (int kb = 0; kb < 32; ++kb) {
        const int t0 = kb * 32 + 8 * lg;
        const bf8 av = ld8(arowp + t0);
        #pragma unroll
        for (int nf = 0; nf < 4; ++nf) {
            const bf8 bv = ld8(base + (size_t)(lm + 16 * nf) * 1024 + t0);
            acc[nf] = __builtin_amdgcn_mfma_f32_16x16x32_bf16(av, bv, acc[nf], 0, 0, 0);
        }
    }
    float part = 0.f;
    #pragma unroll
    for (int nf = 0; nf < 4; ++nf) {
        const int d2 = lm + 16 * nf;
        const float i2 = invn[bh * 64 + d2];
        #pragma unroll
        for (int j = 0; j < 4; ++j) {
            const int d1 = 16 * w + 4 * lg + j;
            const float g = acc[nf][j] * invn[bh * 64 + d1] * i2;
            const float diff = g - ((d1 == d2) ? 1.f : 0.f);
            part = fmaf(diff, diff, part);
        }
    }
    __shared__ float red[256];
    red[tid] = part;
    __syncthreads();
    for (int k = 128; k >= 1; k >>= 1) {
        if (tid < k) red[tid] += red[tid + k];
        __syncthreads();
    }
    if (tid == 0) regp[bh] = red[0];
}

// ---------------------------------------------------------------------------
// Final deterministic reduction
// ---------------------------------------------------------------------------
__global__ __launch_bounds__(256)
void k_final(const float* __restrict__ t1p, const float* __restrict__ t2p,
             const float* __restrict__ regp, float* __restrict__ out_tr,
             float* __restrict__ out_reg)
{
    const int tid = threadIdx.x;
    float s1 = 0.f, s2 = 0.f, s3 = 0.f;
    for (int i = tid; i < 768; i += 256) s2 += t2p[i];
    if (tid < 48) { s1 = t1p[tid]; s3 = regp[tid]; }
    __shared__ float R1[256];
    __shared__ float R2[256];
    __shared__ float R3[256];
    R1[tid] = s1; R2[tid] = s2; R3[tid] = s3;
    __syncthreads();
    for (int w = 128; w >= 1; w >>= 1) {
        if (tid < w) { R1[tid] += R1[tid + w]; R2[tid] += R2[tid + w]; R3[tid] += R3[tid + w]; }
        __syncthreads();
    }
    if (tid == 0) {
        *out_tr  = fabsf(R1[0] - R2[0]) / 3072.f;
        *out_reg = R3[0] / 3072.f;
    }
}

// ---------------------------------------------------------------------------
extern "C" void kernel_launch(void* const* d_in, const int* in_sizes, int n_in,
                              void* d_out, int out_size, void* d_ws, size_t ws_size,
                              hipStream_t stream)
{
    const float* X  = (const float*)d_in[0];
    const float* Wq = (const float*)d_in[1];
    const float* bq = (const float*)d_in[2];
    const float* Wv = (const float*)d_in[3];
    const float* bv = (const float*)d_in[4];
    const float* Wo = (const float*)d_in[5];
    const float* bo = (const float*)d_in[6];

    float* out = (float*)d_out;
    float* att = out;                         // [4096,768]
    float* tr  = out + 3145728;
    float* rg  = out + 3145729;
    float* mq1 = out + 3145730;               // mixed_q (output 3)
    float* mq2 = out + 6291458;               // mixed_q (output 4)

    float* ws = (float*)d_ws;
    unsigned short* mvb  = (unsigned short*)(ws);             // 3.1M u16
    unsigned short* qb   = (unsigned short*)(ws + 1572864);
    unsigned short* vT   = (unsigned short*)(ws + 3145728);
    unsigned short* ctxb = (unsigned short*)(ws + 4718592);
    float* mrow = ws + 6291456;               // [48,1024]
    float* rrow = ws + 6340608;
    float* aarr = ws + 6389760;
    float* Mh   = ws + 6438912;               // [48]
    float* invn = ws + 6438960;               // [48,64]
    float* t1p  = ws + 6442032;               // [48]
    float* t2p  = ws + 6442080;               // [768]
    float* regp = ws + 6442848;               // [48]

    if (ws_size < (size_t)6442896 * sizeof(float)) return;

    k_gemm_qv  <<<dim3(32, 24), 256, 0, stream>>>(X, Wq, bq, Wv, bv, mq1, mq2, qb, mvb);
    k_colnorm  <<<48,           256, 0, stream>>>(mvb, invn, t1p);
    k_transpose<<<dim3(16, 48), 256, 0, stream>>>(mvb, vT);
    k_pass1    <<<dim3(16, 48), 256, 0, stream>>>(qb, mrow, rrow);
    k_amax     <<<48,           256, 0, stream>>>(mrow, rrow, Mh, aarr);
    k_pass2    <<<dim3(16, 48), 256, 0, stream>>>(qb, vT, mvb, aarr, Mh, invn, ctxb, t2p);
    k_reg      <<<48,           256, 0, stream>>>(vT, invn, regp);
    k_final    <<<1,            256, 0, stream>>>(t1p, t2p, regp, tr, rg);
    k_gemm_one <<<dim3(32, 12), 256, 0, stream>>>(ctxb, Wo, bo, att);
}

// Round 3
// 235.773 us; speedup vs baseline: 3.3569x; 1.7622x over previous
//
#include <hip/hip_runtime.h>
#include <math.h>

// Problem constants (ViT-Base): B=4, S=1024, D=768, H=12, HD=64
constexpr float SCALE = 0.125f;               // 1/sqrt(64)

typedef __attribute__((ext_vector_type(8))) short bf8;            // 8 bf16 (4 VGPRs)
typedef __attribute__((ext_vector_type(8))) unsigned short u16x8;
typedef __attribute__((ext_vector_type(4))) float f32x4;

static __device__ __forceinline__ unsigned short f2bf(float f) {
    unsigned int u = __float_as_uint(f);
    u += 0x7fffu + ((u >> 16) & 1u);          // round-to-nearest-even
    return (unsigned short)(u >> 16);
}
static __device__ __forceinline__ float bf2f(unsigned short h) {
    return __uint_as_float(((unsigned int)h) << 16);
}
static __device__ __forceinline__ bf8 ld8(const unsigned short* p) {
    return *reinterpret_cast<const bf8*>(p);
}

// ---------------------------------------------------------------------------
// Cast X (fp32) -> Xb (bf16). 3145728 elems, 8/thread.
// ---------------------------------------------------------------------------
__global__ __launch_bounds__(256)
void k_xcast(const float* __restrict__ X, unsigned short* __restrict__ Xb)
{
    const size_t i0 = ((size_t)blockIdx.x * 256 + threadIdx.x) * 8;
    const float4 a = *reinterpret_cast<const float4*>(X + i0);
    const float4 b = *reinterpret_cast<const float4*>(X + i0 + 4);
    u16x8 o;
    o[0] = f2bf(a.x); o[1] = f2bf(a.y); o[2] = f2bf(a.z); o[3] = f2bf(a.w);
    o[4] = f2bf(b.x); o[5] = f2bf(b.y); o[6] = f2bf(b.z); o[7] = f2bf(b.w);
    *reinterpret_cast<u16x8*>(Xb + i0) = o;
}

// ---------------------------------------------------------------------------
// Transpose + convert one weight: WT[n][k] = bf16(W[k][n]). grid (12,12)
// ---------------------------------------------------------------------------
__global__ __launch_bounds__(256)
void k_wt(const float* __restrict__ W, unsigned short* __restrict__ WT)
{
    __shared__ unsigned short T[64 * 72];
    const int n0 = blockIdx.x * 64;
    const int k0 = blockIdx.y * 64;
    const int tid = threadIdx.x;
    const int r  = tid >> 2;          // k within tile
    const int c0 = (tid & 3) * 16;    // n within tile
    const float* src = &W[(size_t)(k0 + r) * 768 + n0 + c0];
    #pragma unroll
    for (int q = 0; q < 4; ++q) {
        const float4 v = *reinterpret_cast<const float4*>(src + q * 4);
        T[r * 72 + c0 + q * 4 + 0] = f2bf(v.x);
        T[r * 72 + c0 + q * 4 + 1] = f2bf(v.y);
        T[r * 72 + c0 + q * 4 + 2] = f2bf(v.z);
        T[r * 72 + c0 + q * 4 + 3] = f2bf(v.w);
    }
    __syncthreads();
    const int n  = tid >> 2;          // n within tile
    const int kc = (tid & 3) * 16;    // k within tile
    u16x8 o0, o1;
    #pragma unroll
    for (int i = 0; i < 8; ++i) o0[i] = T[(kc + i) * 72 + n];
    #pragma unroll
    for (int i = 0; i < 8; ++i) o1[i] = T[(kc + 8 + i) * 72 + n];
    unsigned short* dst = WT + (size_t)(n0 + n) * 768 + k0 + kc;
    *reinterpret_cast<u16x8*>(dst)     = o0;
    *reinterpret_cast<u16x8*>(dst + 8) = o1;
}

// ---------------------------------------------------------------------------
// GEMM 1 (MFMA bf16): C = Xb @ WT^T + bias. 128x128 tile, BK=64, 4 waves.
// Q blocks (blockIdx.y<6): fp32 mq1,mq2 + bf16 qb.  V blocks: bf16 mvb.
// ---------------------------------------------------------------------------
__global__ __launch_bounds__(256)
void k_gemm_qv(const unsigned short* __restrict__ Xb,
               const unsigned short* __restrict__ WTq,
               const unsigned short* __restrict__ WTv,
               const float* __restrict__ bq, const float* __restrict__ bv,
               float* __restrict__ mq1, float* __restrict__ mq2,
               unsigned short* __restrict__ qb, unsigned short* __restrict__ mvb)
{
    __shared__ unsigned short As[128 * 72];
    __shared__ unsigned short Bs[128 * 72];
    const int m0 = blockIdx.x * 128;
    const bool isQ = (blockIdx.y < 6);
    const int n0 = (isQ ? blockIdx.y : blockIdx.y - 6) * 128;
    const unsigned short* __restrict__ WT = isQ ? WTq : WTv;
    const float* __restrict__ bias = isQ ? bq : bv;
    const int tid = threadIdx.x;
    const int wave = tid >> 6, lane = tid & 63, lm = lane & 15, lg = lane >> 4;
    const int wm = wave & 1, wn = wave >> 1;

    f32x4 acc[4][4];
    #pragma unroll
    for (int mi = 0; mi < 4; ++mi)
        #pragma unroll
        for (int ni = 0; ni < 4; ++ni) acc[mi][ni] = (f32x4){0.f, 0.f, 0.f, 0.f};

    for (int k0 = 0; k0 < 768; k0 += 64) {
        #pragma unroll
        for (int it = 0; it < 4; ++it) {
            const int idx = tid + it * 256;
            const int row = idx >> 3;
            const int c8  = (idx & 7) * 8;
            *reinterpret_cast<u16x8*>(&As[row * 72 + c8]) =
                *reinterpret_cast<const u16x8*>(&Xb[(size_t)(m0 + row) * 768 + k0 + c8]);
            *reinterpret_cast<u16x8*>(&Bs[row * 72 + c8]) =
                *reinterpret_cast<const u16x8*>(&WT[(size_t)(n0 + row) * 768 + k0 + c8]);
        }
        __syncthreads();
        #pragma unroll
        for (int ks = 0; ks < 2; ++ks) {
            bf8 af[4], bfr[4];
            #pragma unroll
            for (int mi = 0; mi < 4; ++mi)
                af[mi] = *reinterpret_cast<const bf8*>(
                    &As[(wm * 64 + mi * 16 + lm) * 72 + ks * 32 + lg * 8]);
            #pragma unroll
            for (int ni = 0; ni < 4; ++ni)
                bfr[ni] = *reinterpret_cast<const bf8*>(
                    &Bs[(wn * 64 + ni * 16 + lm) * 72 + ks * 32 + lg * 8]);
            #pragma unroll
            for (int mi = 0; mi < 4; ++mi)
                #pragma unroll
                for (int ni = 0; ni < 4; ++ni)
                    acc[mi][ni] = __builtin_amdgcn_mfma_f32_16x16x32_bf16(
                        af[mi], bfr[ni], acc[mi][ni], 0, 0, 0);
        }
        __syncthreads();
    }
    #pragma unroll
    for (int ni = 0; ni < 4; ++ni) {
        const int c = n0 + wn * 64 + ni * 16 + lm;
        const float bcol = bias[c];
        #pragma unroll
        for (int mi = 0; mi < 4; ++mi)
            #pragma unroll
            for (int j = 0; j < 4; ++j) {
                const int r = m0 + wm * 64 + mi * 16 + lg * 4 + j;
                const float v = acc[mi][ni][j] + bcol;
                const size_t off = (size_t)r * 768 + c;
                if (isQ) {
                    mq1[off] = v;
                    mq2[off] = v;
                    qb[off]  = f2bf(v);
                } else {
                    mvb[off] = f2bf(v);
                }
            }
    }
}

// ---------------------------------------------------------------------------
// GEMM 2 (MFMA bf16): att = ctxb @ WTo^T + bo (fp32 out). grid (32, 6)
// ---------------------------------------------------------------------------
__global__ __launch_bounds__(256)
void k_gemm_one(const unsigned short* __restrict__ Xb,
                const unsigned short* __restrict__ WT,
                const float* __restrict__ bias, float* __restrict__ out)
{
    __shared__ unsigned short As[128 * 72];
    __shared__ unsigned short Bs[128 * 72];
    const int m0 = blockIdx.x * 128;
    const int n0 = blockIdx.y * 128;
    const int tid = threadIdx.x;
    const int wave = tid >> 6, lane = tid & 63, lm = lane & 15, lg = lane >> 4;
    const int wm = wave & 1, wn = wave >> 1;

    f32x4 acc[4][4];
    #pragma unroll
    for (int mi = 0; mi < 4; ++mi)
        #pragma unroll
        for (int ni = 0; ni < 4; ++ni) acc[mi][ni] = (f32x4){0.f, 0.f, 0.f, 0.f};

    for (int k0 = 0; k0 < 768; k0 += 64) {
        #pragma unroll
        for (int it = 0; it < 4; ++it) {
            const int idx = tid + it * 256;
            const int row = idx >> 3;
            const int c8  = (idx & 7) * 8;
            *reinterpret_cast<u16x8*>(&As[row * 72 + c8]) =
                *reinterpret_cast<const u16x8*>(&Xb[(size_t)(m0 + row) * 768 + k0 + c8]);
            *reinterpret_cast<u16x8*>(&Bs[row * 72 + c8]) =
                *reinterpret_cast<const u16x8*>(&WT[(size_t)(n0 + row) * 768 + k0 + c8]);
        }
        __syncthreads();
        #pragma unroll
        for (int ks = 0; ks < 2; ++ks) {
            bf8 af[4], bfr[4];
            #pragma unroll
            for (int mi = 0; mi < 4; ++mi)
                af[mi] = *reinterpret_cast<const bf8*>(
                    &As[(wm * 64 + mi * 16 + lm) * 72 + ks * 32 + lg * 8]);
            #pragma unroll
            for (int ni = 0; ni < 4; ++ni)
                bfr[ni] = *reinterpret_cast<const bf8*>(
                    &Bs[(wn * 64 + ni * 16 + lm) * 72 + ks * 32 + lg * 8]);
            #pragma unroll
            for (int mi = 0; mi < 4; ++mi)
                #pragma unroll
                for (int ni = 0; ni < 4; ++ni)
                    acc[mi][ni] = __builtin_amdgcn_mfma_f32_16x16x32_bf16(
                        af[mi], bfr[ni], acc[mi][ni], 0, 0, 0);
        }
        __syncthreads();
    }
    #pragma unroll
    for (int ni = 0; ni < 4; ++ni) {
        const int c = n0 + wn * 64 + ni * 16 + lm;
        const float bcol = bias[c];
        #pragma unroll
        for (int mi = 0; mi < 4; ++mi)
            #pragma unroll
            for (int j = 0; j < 4; ++j) {
                const int r = m0 + wm * 64 + mi * 16 + lg * 4 + j;
                out[(size_t)r * 768 + c] = acc[mi][ni][j] + bcol;
            }
    }
}

// ---------------------------------------------------------------------------
// Column norms along sequence + t1 = sum (v*inv)^2 per head
// ---------------------------------------------------------------------------
__global__ __launch_bounds__(256)
void k_colnorm(const unsigned short* __restrict__ mvb, float* __restrict__ inv_n,
               float* __restrict__ t1p)
{
    const int bh = blockIdx.x;
    const int b = bh / 12, h = bh % 12;
    const int tid = threadIdx.x;
    const int d = tid & 63, chunk = tid >> 6;
    const unsigned short* base = mvb + (size_t)b * 1024 * 768 + h * 64 + d;
    float p = 0.f;
    for (int s = chunk * 256; s < chunk * 256 + 256; ++s) {
        const float v = bf2f(base[(size_t)s * 768]);
        p = fmaf(v, v, p);
    }
    __shared__ float red[4][64];
    __shared__ float t1s[64];
    red[chunk][d] = p;
    __syncthreads();
    if (tid < 64) {
        const float sum = red[0][tid] + red[1][tid] + red[2][tid] + red[3][tid];
        const float n = fmaxf(sqrtf(sum), 1e-12f);
        const float iv = 1.f / n;
        inv_n[bh * 64 + tid] = iv;
        t1s[tid] = sum * iv * iv;
    }
    __syncthreads();
    if (tid == 0) {
        float t = 0.f;
        for (int k = 0; k < 64; ++k) t += t1s[k];
        t1p[bh] = t;
    }
}

// ---------------------------------------------------------------------------
// Transpose V per head: vT[bh][d (64)][t (1024)] bf16
// ---------------------------------------------------------------------------
__global__ __launch_bounds__(256)
void k_transpose(const unsigned short* __restrict__ mvb, unsigned short* __restrict__ vT)
{
    __shared__ unsigned short T[64 * 72];
    const int st = blockIdx.x, bh = blockIdx.y;
    const int b = bh / 12, h = bh % 12;
    const int s0 = st * 64;
    const int tid = threadIdx.x;
    const int r  = tid >> 2;
    const int c0 = (tid & 3) * 16;
    const unsigned short* src = mvb + (size_t)(b * 1024 + s0 + r) * 768 + h * 64 + c0;
    const u16x8 x0 = *reinterpret_cast<const u16x8*>(src);
    const u16x8 x1 = *reinterpret_cast<const u16x8*>(src + 8);
    *reinterpret_cast<u16x8*>(&T[r * 72 + c0])     = x0;
    *reinterpret_cast<u16x8*>(&T[r * 72 + c0 + 8]) = x1;
    __syncthreads();
    const int dd  = tid >> 2;
    const int sc0 = (tid & 3) * 16;
    u16x8 o0, o1;
    #pragma unroll
    for (int k = 0; k < 8; ++k) o0[k] = T[(sc0 + k) * 72 + dd];
    #pragma unroll
    for (int k = 0; k < 8; ++k) o1[k] = T[(sc0 + 8 + k) * 72 + dd];
    unsigned short* dst = vT + (size_t)bh * 65536 + (size_t)dd * 1024 + s0 + sc0;
    *reinterpret_cast<u16x8*>(dst)     = o0;
    *reinterpret_cast<u16x8*>(dst + 8) = o1;
}

// ---------------------------------------------------------------------------
// Pass 1 (MFMA): per-row running max m_s and R'_s = sum exp(sc - m_s)
// ---------------------------------------------------------------------------
__global__ __launch_bounds__(256)
void k_pass1(const unsigned short* __restrict__ qb,
             float* __restrict__ mrow, float* __restrict__ rrow)
{
    const int st = blockIdx.x, bh = blockIdx.y;
    const int b = bh / 12, h = bh % 12;
    const int s0 = st * 64;
    const int tid = threadIdx.x;
    const int w = tid >> 6, lane = tid & 63, lm = lane & 15, lg = lane >> 4;
    const size_t qoff = (size_t)(b * 1024) * 768 + h * 64;
    const unsigned short* arow = qb + qoff + (size_t)(s0 + 16 * w + lm) * 768;
    const bf8 a0 = ld8(arow + 8 * lg);
    const bf8 a1 = ld8(arow + 32 + 8 * lg);
    const f32x4 z = {0.f, 0.f, 0.f, 0.f};
    float m_j[4], r_j[4];
    #pragma unroll
    for (int j = 0; j < 4; ++j) { m_j[j] = -1e30f; r_j[j] = 0.f; }

    for (int tt = 0; tt < 16; ++tt) {
        const int t0 = tt * 64;
        f32x4 accf[4];
        #pragma unroll
        for (int nf = 0; nf < 4; ++nf) {
            const unsigned short* brow = qb + qoff + (size_t)(t0 + 16 * nf + lm) * 768;
            const bf8 b0 = ld8(brow + 8 * lg);
            const bf8 b1 = ld8(brow + 32 + 8 * lg);
            f32x4 acc = __builtin_amdgcn_mfma_f32_16x16x32_bf16(a0, b0, z, 0, 0, 0);
            acc = __builtin_amdgcn_mfma_f32_16x16x32_bf16(a1, b1, acc, 0, 0, 0);
            accf[nf] = acc;
        }
        #pragma unroll
        for (int j = 0; j < 4; ++j) {
            const float v0 = accf[0][j] * SCALE, v1 = accf[1][j] * SCALE;
            const float v2 = accf[2][j] * SCALE, v3 = accf[3][j] * SCALE;
            const float lmx = fmaxf(fmaxf(v0, v1), fmaxf(v2, v3));
            const float nm = fmaxf(m_j[j], lmx);
            const float s = __expf(v0 - nm) + __expf(v1 - nm) +
                            __expf(v2 - nm) + __expf(v3 - nm);
            r_j[j] = r_j[j] * __expf(m_j[j] - nm) + s;
            m_j[j] = nm;
        }
    }
    #pragma unroll
    for (int j = 0; j < 4; ++j)
        #pragma unroll
        for (int k = 1; k < 16; k <<= 1) {
            const float om  = __shfl_xor(m_j[j], k);
            const float orr = __shfl_xor(r_j[j], k);
            const float nm = fmaxf(m_j[j], om);
            r_j[j] = r_j[j] * __expf(m_j[j] - nm) + orr * __expf(om - nm);
            m_j[j] = nm;
        }
    if (lm == 0) {
        #pragma unroll
        for (int j = 0; j < 4; ++j) {
            const int srow = s0 + 16 * w + 4 * lg + j;
            mrow[(size_t)bh * 1024 + srow] = m_j[j];
            rrow[(size_t)bh * 1024 + srow] = r_j[j];
        }
    }
}

// ---------------------------------------------------------------------------
// Per-head global max M and a_s = exp(M - m_s)/R'_s
// ---------------------------------------------------------------------------
__global__ __launch_bounds__(256)
void k_amax(const float* __restrict__ mrow, const float* __restrict__ rrow,
            float* __restrict__ Mh, float* __restrict__ a)
{
    const int bh = blockIdx.x;
    const int tid = threadIdx.x;
    float m = -1e30f;
    for (int s = tid; s < 1024; s += 256) m = fmaxf(m, mrow[(size_t)bh * 1024 + s]);
    __shared__ float red[256];
    red[tid] = m;
    __syncthreads();
    for (int w = 128; w >= 1; w >>= 1) {
        if (tid < w) red[tid] = fmaxf(red[tid], red[tid + w]);
        __syncthreads();
    }
    const float M = red[0];
    if (tid == 0) Mh[bh] = M;
    for (int s = tid; s < 1024; s += 256)
        a[(size_t)bh * 1024 + s] =
            __expf(M - mrow[(size_t)bh * 1024 + s]) / rrow[(size_t)bh * 1024 + s];
}

// ---------------------------------------------------------------------------
// Pass 2 (MFMA): E=exp(sc-M); ctx1=E@V, ctx2=E@(a.V); g=E@a; ctx + t2 partials
// ---------------------------------------------------------------------------
__global__ __launch_bounds__(256)
void k_pass2(const unsigned short* __restrict__ qb,
             const unsigned short* __restrict__ vT,
             const unsigned short* __restrict__ mvb,
             const float* __restrict__ a, const float* __restrict__ Mh,
             const float* __restrict__ invn,
             unsigned short* __restrict__ ctxb,
             float* __restrict__ t2p)
{
    __shared__ unsigned short E_lds[64 * 72];
    __shared__ unsigned short Vt_lds[64 * 72];
    __shared__ unsigned short Va_lds[64 * 72];
    __shared__ float red[256];
    const int st = blockIdx.x, bh = blockIdx.y;
    const int b = bh / 12, h = bh % 12;
    const int s0 = st * 64;
    const int tid = threadIdx.x;
    const int w = tid >> 6, lane = tid & 63, lm = lane & 15, lg = lane >> 4;
    const float Mhead = Mh[bh];
    const size_t qoff = (size_t)(b * 1024) * 768 + h * 64;
    const unsigned short* arow_p = qb + qoff + (size_t)(s0 + 16 * w + lm) * 768;
    const bf8 qa0 = ld8(arow_p + 8 * lg);
    const bf8 qa1 = ld8(arow_p + 32 + 8 * lg);
    const int vrow = tid >> 2;
    const int tcol = (tid & 3) * 16;
    const unsigned short* vTbase = vT + (size_t)bh * 65536 + (size_t)vrow * 1024;
    const float* abase = a + (size_t)bh * 1024;
    float inv2[4];
    #pragma unroll
    for (int nf = 0; nf < 4; ++nf) {
        const float iv = invn[bh * 64 + lm + 16 * nf];
        inv2[nf] = iv * iv;
    }
    const f32x4 z = {0.f, 0.f, 0.f, 0.f};
    f32x4 acc1[4], acc2[4];
    #pragma unroll
    for (int nf = 0; nf < 4; ++nf) { acc1[nf] = z; acc2[nf] = z; }
    float gpart[4] = {0.f, 0.f, 0.f, 0.f};

    for (int tt = 0; tt < 16; ++tt) {
        const int t0 = tt * 64;
        const u16x8 v0 = *reinterpret_cast<const u16x8*>(vTbase + t0 + tcol);
        const u16x8 v1 = *reinterpret_cast<const u16x8*>(vTbase + t0 + tcol + 8);
        const float4 af0 = *reinterpret_cast<const float4*>(abase + t0 + tcol);
        const float4 af1 = *reinterpret_cast<const float4*>(abase + t0 + tcol + 4);
        const float4 af2 = *reinterpret_cast<const float4*>(abase + t0 + tcol + 8);
        const float4 af3 = *reinterpret_cast<const float4*>(abase + t0 + tcol + 12);
        f32x4 ef[4];
        #pragma unroll
        for (int nf = 0; nf < 4; ++nf) {
            const unsigned short* brow = qb + qoff + (size_t)(t0 + 16 * nf + lm) * 768;
            const bf8 b0 = ld8(brow + 8 * lg);
            const bf8 b1 = ld8(brow + 32 + 8 * lg);
            f32x4 acc = __builtin_amdgcn_mfma_f32_16x16x32_bf16(qa0, b0, z, 0, 0, 0);
            acc = __builtin_amdgcn_mfma_f32_16x16x32_bf16(qa1, b1, acc, 0, 0, 0);
            ef[nf] = acc;
        }
        float e_val[4][4];
        #pragma unroll
        for (int nf = 0; nf < 4; ++nf) {
            const float ac = abase[t0 + 16 * nf + lm];
            #pragma unroll
            for (int j = 0; j < 4; ++j) {
                const float e = __expf(ef[nf][j] * SCALE - Mhead);
                e_val[nf][j] = e;
                gpart[j] = fmaf(e, ac, gpart[j]);
            }
        }
        __syncthreads();
        #pragma unroll
        for (int nf = 0; nf < 4; ++nf)
            #pragma unroll
            for (int j = 0; j < 4; ++j)
                E_lds[(16 * w + 4 * lg + j) * 72 + lm + 16 * nf] = f2bf(e_val[nf][j]);
        *reinterpret_cast<u16x8*>(&Vt_lds[vrow * 72 + tcol])     = v0;
        *reinterpret_cast<u16x8*>(&Vt_lds[vrow * 72 + tcol + 8]) = v1;
        u16x8 w0, w1;
        w0[0] = f2bf(bf2f(v0[0]) * af0.x); w0[1] = f2bf(bf2f(v0[1]) * af0.y);
        w0[2] = f2bf(bf2f(v0[2]) * af0.z); w0[3] = f2bf(bf2f(v0[3]) * af0.w);
        w0[4] = f2bf(bf2f(v0[4]) * af1.x); w0[5] = f2bf(bf2f(v0[5]) * af1.y);
        w0[6] = f2bf(bf2f(v0[6]) * af1.z); w0[7] = f2bf(bf2f(v0[7]) * af1.w);
        w1[0] = f2bf(bf2f(v1[0]) * af2.x); w1[1] = f2bf(bf2f(v1[1]) * af2.y);
        w1[2] = f2bf(bf2f(v1[2]) * af2.z); w1[3] = f2bf(bf2f(v1[3]) * af2.w);
        w1[4] = f2bf(bf2f(v1[4]) * af3.x); w1[5] = f2bf(bf2f(v1[5]) * af3.y);
        w1[6] = f2bf(bf2f(v1[6]) * af3.z); w1[7] = f2bf(bf2f(v1[7]) * af3.w);
        *reinterpret_cast<u16x8*>(&Va_lds[vrow * 72 + tcol])     = w0;
        *reinterpret_cast<u16x8*>(&Va_lds[vrow * 72 + tcol + 8]) = w1;
        __syncthreads();
        #pragma unroll
        for (int ks = 0; ks < 2; ++ks) {
            const bf8 ae = *reinterpret_cast<const bf8*>(
                &E_lds[(16 * w + lm) * 72 + 32 * ks + 8 * lg]);
            #pragma unroll
            for (int nf = 0; nf < 4; ++nf) {
                const bf8 bv = *reinterpret_cast<const bf8*>(
                    &Vt_lds[(lm + 16 * nf) * 72 + 32 * ks + 8 * lg]);
                const bf8 ba = *reinterpret_cast<const bf8*>(
                    &Va_lds[(lm + 16 * nf) * 72 + 32 * ks + 8 * lg]);
                acc1[nf] = __builtin_amdgcn_mfma_f32_16x16x32_bf16(ae, bv, acc1[nf], 0, 0, 0);
                acc2[nf] = __builtin_amdgcn_mfma_f32_16x16x32_bf16(ae, ba, acc2[nf], 0, 0, 0);
            }
        }
    }
    #pragma unroll
    for (int j = 0; j < 4; ++j)
        #pragma unroll
        for (int k = 1; k < 16; k <<= 1)
            gpart[j] += __shfl_xor(gpart[j], k);

    float t2 = 0.f;
    #pragma unroll
    for (int j = 0; j < 4; ++j) {
        const int srow = s0 + 16 * w + 4 * lg + j;
        const float arow = abase[srow];
        const float rdv = 1.f / (0.5f * (1.f + gpart[j]));
        const size_t rowoff = (size_t)(b * 1024 + srow) * 768 + h * 64;
        #pragma unroll
        for (int nf = 0; nf < 4; ++nf) {
            const int d = lm + 16 * nf;
            const float cf = 0.5f * (arow * acc1[nf][j] + acc2[nf][j]);
            ctxb[rowoff + d] = f2bf(cf);
            const float vv = bf2f(mvb[rowoff + d]);
            t2 = fmaf(vv * cf, inv2[nf] * rdv, t2);
        }
    }
    red[tid] = t2;
    __syncthreads();
    for (int k = 128; k >= 1; k >>= 1) {
        if (tid < k) red[tid] += red[tid + k];
        __syncthreads();
    }
    if (tid == 0) t2p[bh * 16 + st] = red[0];
}

// ---------------------------------------------------------------------------
// Orthogonality term via MFMA Gram from vT: sum (VtV - I)^2 per head
// ---------------------------------------------------------------------------
__global__ __launch_bounds__(256)
void k_reg(const unsigned short* __restrict__ vT, const float* __restrict__ invn,
           float* __restrict__ regp)
{
    const int bh = blockIdx.x;
    const int tid = threadIdx.x;
    const int w = tid >> 6, lane = tid & 63, lm = lane & 15, lg = lane >> 4;
    const unsigned short* base = vT + (size_t)bh * 65536;
    const unsigned short* arowp = base + (size_t)(16 * w + lm) * 1024;
    const f32x4 z = {0.f, 0.f, 0.f, 0.f};
    f32x4 acc[4];
    #pragma unroll
    for (int nf = 0; nf < 4; ++nf) acc[nf] = z;
    for (int kb = 0; kb < 32; ++kb) {
        const int t0 = kb * 32 + 8 * lg;
        const bf8 av = ld8(arowp + t0);
        #pragma unroll
        for (int nf = 0; nf < 4; ++nf) {
            const bf8 bv = ld8(base + (size_t)(lm + 16 * nf) * 1024 + t0);
            acc[nf] = __builtin_amdgcn_mfma_f32_16x16x32_bf16(av, bv, acc[nf], 0, 0, 0);
        }
    }
    float part = 0.f;
    #pragma unroll
    for (int nf = 0; nf < 4; ++nf) {
        const int d2 = lm + 16 * nf;
        const float i2 = invn[bh * 64 + d2];
        #pragma unroll
        for (int j = 0; j < 4; ++j) {
            const int d1 = 16 * w + 4 * lg + j;
            const float g = acc[nf][j] * invn[bh * 64 + d1] * i2;
            const float diff = g - ((d1 == d2) ? 1.f : 0.f);
            part = fmaf(diff, diff, part);
        }
    }
    __shared__ float red[256];
    red[tid] = part;
    __syncthreads();
    for (int k = 128; k >= 1; k >>= 1) {
        if (tid < k) red[tid] += red[tid + k];
        __syncthreads();
    }
    if (tid == 0) regp[bh] = red[0];
}

// ---------------------------------------------------------------------------
// Final deterministic reduction
// ---------------------------------------------------------------------------
__global__ __launch_bounds__(256)
void k_final(const float* __restrict__ t1p, const float* __restrict__ t2p,
             const float* __restrict__ regp, float* __restrict__ out_tr,
             float* __restrict__ out_reg)
{
    const int tid = threadIdx.x;
    float s1 = 0.f, s2 = 0.f, s3 = 0.f;
    for (int i = tid; i < 768; i += 256) s2 += t2p[i];
    if (tid < 48) { s1 = t1p[tid]; s3 = regp[tid]; }
    __shared__ float R1[256];
    __shared__ float R2[256];
    __shared__ float R3[256];
    R1[tid] = s1; R2[tid] = s2; R3[tid] = s3;
    __syncthreads();
    for (int w = 128; w >= 1; w >>= 1) {
        if (tid < w) { R1[tid] += R1[tid + w]; R2[tid] += R2[tid + w]; R3[tid] += R3[tid + w]; }
        __syncthreads();
    }
    if (tid == 0) {
        *out_tr  = fabsf(R1[0] - R2[0]) / 3072.f;
        *out_reg = R3[0] / 3072.f;
    }
}

// ---------------------------------------------------------------------------
extern "C" void kernel_launch(void* const* d_in, const int* in_sizes, int n_in,
                              void* d_out, int out_size, void* d_ws, size_t ws_size,
                              hipStream_t stream)
{
    const float* X  = (const float*)d_in[0];
    const float* Wq = (const float*)d_in[1];
    const float* bq = (const float*)d_in[2];
    const float* Wv = (const float*)d_in[3];
    const float* bv = (const float*)d_in[4];
    const float* Wo = (const float*)d_in[5];
    const float* bo = (const float*)d_in[6];

    float* out = (float*)d_out;
    float* att = out;                         // [4096,768]
    float* tr  = out + 3145728;
    float* rg  = out + 3145729;
    float* mq1 = out + 3145730;               // mixed_q (output 3)
    float* mq2 = out + 6291458;               // mixed_q (output 4)

    float* ws = (float*)d_ws;
    // Liveness-aliased layout (ws requirement unchanged at ~25.8 MB):
    unsigned short* mvb  = (unsigned short*)(ws);             // [4096,768] bf16
    unsigned short* qb   = (unsigned short*)(ws + 1572864);   // [4096,768] bf16
    // vT slot: WTq/WTv live until k_gemm_qv; vT until k_reg; then WTo.
    unsigned short* vTslot = (unsigned short*)(ws + 3145728); // 3.1M u16
    unsigned short* WTq  = vTslot;                            // [768,768] bf16
    unsigned short* WTv  = vTslot + 589824;
    unsigned short* vT   = vTslot;
    unsigned short* WTo  = vTslot;
    // Xb lives until k_gemm_qv; ctxb written by k_pass2 afterwards.
    unsigned short* Xb   = (unsigned short*)(ws + 4718592);   // [4096,768] bf16
    unsigned short* ctxb = (unsigned short*)(ws + 4718592);
    float* mrow = ws + 6291456;               // [48,1024]
    float* rrow = ws + 6340608;
    float* aarr = ws + 6389760;
    float* Mh   = ws + 6438912;               // [48]
    float* invn = ws + 6438960;               // [48,64]
    float* t1p  = ws + 6442032;               // [48]
    float* t2p  = ws + 6442080;               // [768]
    float* regp = ws + 6442848;               // [48]

    if (ws_size < (size_t)6442896 * sizeof(float)) return;

    k_xcast    <<<1536,         256, 0, stream>>>(X, Xb);
    k_wt       <<<dim3(12, 12), 256, 0, stream>>>(Wq, WTq);
    k_wt       <<<dim3(12, 12), 256, 0, stream>>>(Wv, WTv);
    k_gemm_qv  <<<dim3(32, 12), 256, 0, stream>>>(Xb, WTq, WTv, bq, bv, mq1, mq2, qb, mvb);
    k_colnorm  <<<48,           256, 0, stream>>>(mvb, invn, t1p);
    k_transpose<<<dim3(16, 48), 256, 0, stream>>>(mvb, vT);
    k_pass1    <<<dim3(16, 48), 256, 0, stream>>>(qb, mrow, rrow);
    k_amax     <<<48,           256, 0, stream>>>(mrow, rrow, Mh, aarr);
    k_pass2    <<<dim3(16, 48), 256, 0, stream>>>(qb, vT, mvb, aarr, Mh, invn, ctxb, t2p);
    k_reg      <<<48,           256, 0, stream>>>(vT, invn, regp);
    k_final    <<<1,            256, 0, stream>>>(t1p, t2p, regp, tr, rg);
    k_wt       <<<dim3(12, 12), 256, 0, stream>>>(Wo, WTo);
    k_gemm_one <<<dim3(32, 6),  256, 0, stream>>>(ctxb, WTo, bo, att);
}

// Round 4
// 225.831 us; speedup vs baseline: 3.5047x; 1.0440x over previous
//
#include <hip/hip_runtime.h>
#include <math.h>

// Problem constants (ViT-Base): B=4, S=1024, D=768, H=12, HD=64
constexpr float SCALE = 0.125f;               // 1/sqrt(64)

typedef __attribute__((ext_vector_type(8))) short bf8;            // 8 bf16 (4 VGPRs)
typedef __attribute__((ext_vector_type(8))) unsigned short u16x8;
typedef __attribute__((ext_vector_type(4))) float f32x4;

static __device__ __forceinline__ unsigned short f2bf(float f) {
    unsigned int u = __float_as_uint(f);
    u += 0x7fffu + ((u >> 16) & 1u);          // round-to-nearest-even
    return (unsigned short)(u >> 16);
}
static __device__ __forceinline__ float bf2f(unsigned short h) {
    return __uint_as_float(((unsigned int)h) << 16);
}
static __device__ __forceinline__ bf8 ld8(const unsigned short* p) {
    return *reinterpret_cast<const bf8*>(p);
}

// ---------------------------------------------------------------------------
// Cast X (fp32) -> Xb (bf16). 3145728 elems, 8/thread.
// ---------------------------------------------------------------------------
__global__ __launch_bounds__(256)
void k_xcast(const float* __restrict__ X, unsigned short* __restrict__ Xb)
{
    const size_t i0 = ((size_t)blockIdx.x * 256 + threadIdx.x) * 8;
    const float4 a = *reinterpret_cast<const float4*>(X + i0);
    const float4 b = *reinterpret_cast<const float4*>(X + i0 + 4);
    u16x8 o;
    o[0] = f2bf(a.x); o[1] = f2bf(a.y); o[2] = f2bf(a.z); o[3] = f2bf(a.w);
    o[4] = f2bf(b.x); o[5] = f2bf(b.y); o[6] = f2bf(b.z); o[7] = f2bf(b.w);
    *reinterpret_cast<u16x8*>(Xb + i0) = o;
}

// ---------------------------------------------------------------------------
// Transpose + convert one weight: WT[n][k] = bf16(W[k][n]). grid (12,12)
// ---------------------------------------------------------------------------
__global__ __launch_bounds__(256)
void k_wt(const float* __restrict__ W, unsigned short* __restrict__ WT)
{
    __shared__ unsigned short T[64 * 72];
    const int n0 = blockIdx.x * 64;
    const int k0 = blockIdx.y * 64;
    const int tid = threadIdx.x;
    const int r  = tid >> 2;          // k within tile
    const int c0 = (tid & 3) * 16;    // n within tile
    const float* src = &W[(size_t)(k0 + r) * 768 + n0 + c0];
    #pragma unroll
    for (int q = 0; q < 4; ++q) {
        const float4 v = *reinterpret_cast<const float4*>(src + q * 4);
        T[r * 72 + c0 + q * 4 + 0] = f2bf(v.x);
        T[r * 72 + c0 + q * 4 + 1] = f2bf(v.y);
        T[r * 72 + c0 + q * 4 + 2] = f2bf(v.z);
        T[r * 72 + c0 + q * 4 + 3] = f2bf(v.w);
    }
    __syncthreads();
    const int n  = tid >> 2;          // n within tile
    const int kc = (tid & 3) * 16;    // k within tile
    u16x8 o0, o1;
    #pragma unroll
    for (int i = 0; i < 8; ++i) o0[i] = T[(kc + i) * 72 + n];
    #pragma unroll
    for (int i = 0; i < 8; ++i) o1[i] = T[(kc + 8 + i) * 72 + n];
    unsigned short* dst = WT + (size_t)(n0 + n) * 768 + k0 + kc;
    *reinterpret_cast<u16x8*>(dst)     = o0;
    *reinterpret_cast<u16x8*>(dst + 8) = o1;
}

// ---------------------------------------------------------------------------
// GEMM 1 (MFMA bf16): C = Xb @ WT^T + bias. 128x128 tile, BK=64, 4 waves.
// Q blocks (blockIdx.y<6): fp32 mq1,mq2 + bf16 qb.  V blocks: bf16 mvb.
// ---------------------------------------------------------------------------
__global__ __launch_bounds__(256)
void k_gemm_qv(const unsigned short* __restrict__ Xb,
               const unsigned short* __restrict__ WTq,
               const unsigned short* __restrict__ WTv,
               const float* __restrict__ bq, const float* __restrict__ bv,
               float* __restrict__ mq1, float* __restrict__ mq2,
               unsigned short* __restrict__ qb, unsigned short* __restrict__ mvb)
{
    __shared__ unsigned short As[128 * 72];
    __shared__ unsigned short Bs[128 * 72];
    const int m0 = blockIdx.x * 128;
    const bool isQ = (blockIdx.y < 6);
    const int n0 = (isQ ? blockIdx.y : blockIdx.y - 6) * 128;
    const unsigned short* __restrict__ WT = isQ ? WTq : WTv;
    const float* __restrict__ bias = isQ ? bq : bv;
    const int tid = threadIdx.x;
    const int wave = tid >> 6, lane = tid & 63, lm = lane & 15, lg = lane >> 4;
    const int wm = wave & 1, wn = wave >> 1;

    f32x4 acc[4][4];
    #pragma unroll
    for (int mi = 0; mi < 4; ++mi)
        #pragma unroll
        for (int ni = 0; ni < 4; ++ni) acc[mi][ni] = (f32x4){0.f, 0.f, 0.f, 0.f};

    for (int k0 = 0; k0 < 768; k0 += 64) {
        #pragma unroll
        for (int it = 0; it < 4; ++it) {
            const int idx = tid + it * 256;
            const int row = idx >> 3;
            const int c8  = (idx & 7) * 8;
            *reinterpret_cast<u16x8*>(&As[row * 72 + c8]) =
                *reinterpret_cast<const u16x8*>(&Xb[(size_t)(m0 + row) * 768 + k0 + c8]);
            *reinterpret_cast<u16x8*>(&Bs[row * 72 + c8]) =
                *reinterpret_cast<const u16x8*>(&WT[(size_t)(n0 + row) * 768 + k0 + c8]);
        }
        __syncthreads();
        #pragma unroll
        for (int ks = 0; ks < 2; ++ks) {
            bf8 af[4], bfr[4];
            #pragma unroll
            for (int mi = 0; mi < 4; ++mi)
                af[mi] = *reinterpret_cast<const bf8*>(
                    &As[(wm * 64 + mi * 16 + lm) * 72 + ks * 32 + lg * 8]);
            #pragma unroll
            for (int ni = 0; ni < 4; ++ni)
                bfr[ni] = *reinterpret_cast<const bf8*>(
                    &Bs[(wn * 64 + ni * 16 + lm) * 72 + ks * 32 + lg * 8]);
            #pragma unroll
            for (int mi = 0; mi < 4; ++mi)
                #pragma unroll
                for (int ni = 0; ni < 4; ++ni)
                    acc[mi][ni] = __builtin_amdgcn_mfma_f32_16x16x32_bf16(
                        af[mi], bfr[ni], acc[mi][ni], 0, 0, 0);
        }
        __syncthreads();
    }
    #pragma unroll
    for (int ni = 0; ni < 4; ++ni) {
        const int c = n0 + wn * 64 + ni * 16 + lm;
        const float bcol = bias[c];
        #pragma unroll
        for (int mi = 0; mi < 4; ++mi)
            #pragma unroll
            for (int j = 0; j < 4; ++j) {
                const int r = m0 + wm * 64 + mi * 16 + lg * 4 + j;
                const float v = acc[mi][ni][j] + bcol;
                const size_t off = (size_t)r * 768 + c;
                if (isQ) {
                    mq1[off] = v;
                    mq2[off] = v;
                    qb[off]  = f2bf(v);
                } else {
                    mvb[off] = f2bf(v);
                }
            }
    }
}

// ---------------------------------------------------------------------------
// GEMM 2 (MFMA bf16): att = ctxb @ WTo^T + bo (fp32 out). grid (32, 6)
// ---------------------------------------------------------------------------
__global__ __launch_bounds__(256)
void k_gemm_one(const unsigned short* __restrict__ Xb,
                const unsigned short* __restrict__ WT,
                const float* __restrict__ bias, float* __restrict__ out)
{
    __shared__ unsigned short As[128 * 72];
    __shared__ unsigned short Bs[128 * 72];
    const int m0 = blockIdx.x * 128;
    const int n0 = blockIdx.y * 128;
    const int tid = threadIdx.x;
    const int wave = tid >> 6, lane = tid & 63, lm = lane & 15, lg = lane >> 4;
    const int wm = wave & 1, wn = wave >> 1;

    f32x4 acc[4][4];
    #pragma unroll
    for (int mi = 0; mi < 4; ++mi)
        #pragma unroll
        for (int ni = 0; ni < 4; ++ni) acc[mi][ni] = (f32x4){0.f, 0.f, 0.f, 0.f};

    for (int k0 = 0; k0 < 768; k0 += 64) {
        #pragma unroll
        for (int it = 0; it < 4; ++it) {
            const int idx = tid + it * 256;
            const int row = idx >> 3;
            const int c8  = (idx & 7) * 8;
            *reinterpret_cast<u16x8*>(&As[row * 72 + c8]) =
                *reinterpret_cast<const u16x8*>(&Xb[(size_t)(m0 + row) * 768 + k0 + c8]);
            *reinterpret_cast<u16x8*>(&Bs[row * 72 + c8]) =
                *reinterpret_cast<const u16x8*>(&WT[(size_t)(n0 + row) * 768 + k0 + c8]);
        }
        __syncthreads();
        #pragma unroll
        for (int ks = 0; ks < 2; ++ks) {
            bf8 af[4], bfr[4];
            #pragma unroll
            for (int mi = 0; mi < 4; ++mi)
                af[mi] = *reinterpret_cast<const bf8*>(
                    &As[(wm * 64 + mi * 16 + lm) * 72 + ks * 32 + lg * 8]);
            #pragma unroll
            for (int ni = 0; ni < 4; ++ni)
                bfr[ni] = *reinterpret_cast<const bf8*>(
                    &Bs[(wn * 64 + ni * 16 + lm) * 72 + ks * 32 + lg * 8]);
            #pragma unroll
            for (int mi = 0; mi < 4; ++mi)
                #pragma unroll
                for (int ni = 0; ni < 4; ++ni)
                    acc[mi][ni] = __builtin_amdgcn_mfma_f32_16x16x32_bf16(
                        af[mi], bfr[ni], acc[mi][ni], 0, 0, 0);
        }
        __syncthreads();
    }
    #pragma unroll
    for (int ni = 0; ni < 4; ++ni) {
        const int c = n0 + wn * 64 + ni * 16 + lm;
        const float bcol = bias[c];
        #pragma unroll
        for (int mi = 0; mi < 4; ++mi)
            #pragma unroll
            for (int j = 0; j < 4; ++j) {
                const int r = m0 + wm * 64 + mi * 16 + lg * 4 + j;
                out[(size_t)r * 768 + c] = acc[mi][ni][j] + bcol;
            }
    }
}

// ---------------------------------------------------------------------------
// Column norms along sequence + t1 = sum (v*inv)^2 per head
// ---------------------------------------------------------------------------
__global__ __launch_bounds__(256)
void k_colnorm(const unsigned short* __restrict__ mvb, float* __restrict__ inv_n,
               float* __restrict__ t1p)
{
    const int bh = blockIdx.x;
    const int b = bh / 12, h = bh % 12;
    const int tid = threadIdx.x;
    const int d = tid & 63, chunk = tid >> 6;
    const unsigned short* base = mvb + (size_t)b * 1024 * 768 + h * 64 + d;
    float p = 0.f;
    for (int s = chunk * 256; s < chunk * 256 + 256; ++s) {
        const float v = bf2f(base[(size_t)s * 768]);
        p = fmaf(v, v, p);
    }
    __shared__ float red[4][64];
    __shared__ float t1s[64];
    red[chunk][d] = p;
    __syncthreads();
    if (tid < 64) {
        const float sum = red[0][tid] + red[1][tid] + red[2][tid] + red[3][tid];
        const float n = fmaxf(sqrtf(sum), 1e-12f);
        const float iv = 1.f / n;
        inv_n[bh * 64 + tid] = iv;
        t1s[tid] = sum * iv * iv;
    }
    __syncthreads();
    if (tid == 0) {
        float t = 0.f;
        for (int k = 0; k < 64; ++k) t += t1s[k];
        t1p[bh] = t;
    }
}

// ---------------------------------------------------------------------------
// Transpose V per head: vT[bh][d (64)][t (1024)] bf16
// ---------------------------------------------------------------------------
__global__ __launch_bounds__(256)
void k_transpose(const unsigned short* __restrict__ mvb, unsigned short* __restrict__ vT)
{
    __shared__ unsigned short T[64 * 72];
    const int st = blockIdx.x, bh = blockIdx.y;
    const int b = bh / 12, h = bh % 12;
    const int s0 = st * 64;
    const int tid = threadIdx.x;
    const int r  = tid >> 2;
    const int c0 = (tid & 3) * 16;
    const unsigned short* src = mvb + (size_t)(b * 1024 + s0 + r) * 768 + h * 64 + c0;
    const u16x8 x0 = *reinterpret_cast<const u16x8*>(src);
    const u16x8 x1 = *reinterpret_cast<const u16x8*>(src + 8);
    *reinterpret_cast<u16x8*>(&T[r * 72 + c0])     = x0;
    *reinterpret_cast<u16x8*>(&T[r * 72 + c0 + 8]) = x1;
    __syncthreads();
    const int dd  = tid >> 2;
    const int sc0 = (tid & 3) * 16;
    u16x8 o0, o1;
    #pragma unroll
    for (int k = 0; k < 8; ++k) o0[k] = T[(sc0 + k) * 72 + dd];
    #pragma unroll
    for (int k = 0; k < 8; ++k) o1[k] = T[(sc0 + 8 + k) * 72 + dd];
    unsigned short* dst = vT + (size_t)bh * 65536 + (size_t)dd * 1024 + s0 + sc0;
    *reinterpret_cast<u16x8*>(dst)     = o0;
    *reinterpret_cast<u16x8*>(dst + 8) = o1;
}

// ---------------------------------------------------------------------------
// Pass 1 (MFMA, no-max): a_s = 1/(sum_t exp(sc/8)). Register double-buffered.
// grid (16, 48), 4 waves.
// ---------------------------------------------------------------------------
#define P1_LOAD(tt, d0, d1)                                                   \
    {   const int t0_ = (tt) * 64;                                            \
        _Pragma("unroll")                                                     \
        for (int nf = 0; nf < 4; ++nf) {                                      \
            const unsigned short* brow_ = qb + qoff +                         \
                (size_t)(t0_ + 16 * nf + lm) * 768;                           \
            d0[nf] = ld8(brow_ + 8 * lg);                                     \
            d1[nf] = ld8(brow_ + 32 + 8 * lg);                                \
        } }

#define P1_COMP(b0, b1)                                                       \
    {   f32x4 accf_[4];                                                       \
        _Pragma("unroll")                                                     \
        for (int nf = 0; nf < 4; ++nf) {                                      \
            f32x4 t_ = __builtin_amdgcn_mfma_f32_16x16x32_bf16(a0, b0[nf], z, 0, 0, 0); \
            accf_[nf] = __builtin_amdgcn_mfma_f32_16x16x32_bf16(a1, b1[nf], t_, 0, 0, 0); \
        }                                                                     \
        _Pragma("unroll")                                                     \
        for (int j = 0; j < 4; ++j)                                           \
            r_j[j] += __expf(accf_[0][j] * SCALE) + __expf(accf_[1][j] * SCALE) \
                    + __expf(accf_[2][j] * SCALE) + __expf(accf_[3][j] * SCALE); \
    }

__global__ __launch_bounds__(256)
void k_pass1(const unsigned short* __restrict__ qb, float* __restrict__ a)
{
    const int st = blockIdx.x, bh = blockIdx.y;
    const int b = bh / 12, h = bh % 12;
    const int s0 = st * 64;
    const int tid = threadIdx.x;
    const int w = tid >> 6, lane = tid & 63, lm = lane & 15, lg = lane >> 4;
    const size_t qoff = (size_t)(b * 1024) * 768 + h * 64;
    const unsigned short* arow = qb + qoff + (size_t)(s0 + 16 * w + lm) * 768;
    const bf8 a0 = ld8(arow + 8 * lg);
    const bf8 a1 = ld8(arow + 32 + 8 * lg);
    const f32x4 z = {0.f, 0.f, 0.f, 0.f};
    float r_j[4] = {0.f, 0.f, 0.f, 0.f};

    bf8 bA0[4], bA1[4], bB0[4], bB1[4];
    P1_LOAD(0, bA0, bA1);
    for (int tt = 0; tt < 16; tt += 2) {
        P1_LOAD(tt + 1, bB0, bB1);
        P1_COMP(bA0, bA1);
        if (tt + 2 < 16) P1_LOAD(tt + 2, bA0, bA1);
        P1_COMP(bB0, bB1);
    }
    #pragma unroll
    for (int j = 0; j < 4; ++j)
        #pragma unroll
        for (int k = 1; k < 16; k <<= 1)
            r_j[j] += __shfl_xor(r_j[j], k);
    if (lm == 0) {
        #pragma unroll
        for (int j = 0; j < 4; ++j) {
            const int srow = s0 + 16 * w + 4 * lg + j;
            a[(size_t)bh * 1024 + srow] = 1.f / r_j[j];
        }
    }
}

// ---------------------------------------------------------------------------
// Pass 2 (MFMA, no-max): E=exp(sc/8); ctx1=E@V, ctx2=(E.a_t)@V via Ea tile;
// g=E@a; ctx + t2 partials. XOR-swizzled E/Ea stores (key=(row>>2)&3).
// ---------------------------------------------------------------------------
#define P2_LOAD(tt, d0, d1, vv0, vv1, ac)                                     \
    {   const int t0_ = (tt) * 64;                                            \
        _Pragma("unroll")                                                     \
        for (int nf = 0; nf < 4; ++nf) {                                      \
            const unsigned short* brow_ = qb + qoff +                         \
                (size_t)(t0_ + 16 * nf + lm) * 768;                           \
            d0[nf] = ld8(brow_ + 8 * lg);                                     \
            d1[nf] = ld8(brow_ + 32 + 8 * lg);                                \
            ac[nf] = abase[t0_ + 16 * nf + lm];                               \
        }                                                                     \
        vv0 = *reinterpret_cast<const u16x8*>(vTbase + t0_ + tcol);           \
        vv1 = *reinterpret_cast<const u16x8*>(vTbase + t0_ + tcol + 8);       \
    }

#define P2_COMP(b0, b1, vv0, vv1, ac)                                         \
    {   f32x4 ef_[4];                                                         \
        _Pragma("unroll")                                                     \
        for (int nf = 0; nf < 4; ++nf) {                                      \
            f32x4 t_ = __builtin_amdgcn_mfma_f32_16x16x32_bf16(qa0, b0[nf], z, 0, 0, 0); \
            ef_[nf] = __builtin_amdgcn_mfma_f32_16x16x32_bf16(qa1, b1[nf], t_, 0, 0, 0); \
        }                                                                     \
        unsigned short epk_[4][4], eapk_[4][4];                               \
        _Pragma("unroll")                                                     \
        for (int nf = 0; nf < 4; ++nf) {                                      \
            _Pragma("unroll")                                                 \
            for (int j = 0; j < 4; ++j) {                                     \
                const float e_ = __expf(ef_[nf][j] * SCALE);                  \
                gpart[j] = fmaf(e_, ac[nf], gpart[j]);                        \
                epk_[nf][j]  = f2bf(e_);                                      \
                eapk_[nf][j] = f2bf(e_ * ac[nf]);                             \
            }                                                                 \
        }                                                                     \
        __syncthreads();                                                      \
        _Pragma("unroll")                                                     \
        for (int nf = 0; nf < 4; ++nf) {                                      \
            _Pragma("unroll")                                                 \
            for (int j = 0; j < 4; ++j) {                                     \
                const int row_  = 16 * w + 4 * lg + j;                        \
                const int colx_ = (lm + 16 * nf) ^ (lg << 3);                 \
                E_lds [row_ * 72 + colx_] = epk_[nf][j];                      \
                Ea_lds[row_ * 72 + colx_] = eapk_[nf][j];                     \
            }                                                                 \
        }                                                                     \
        *reinterpret_cast<u16x8*>(&Vt_lds[vrow * 72 + tcol])     = vv0;       \
        *reinterpret_cast<u16x8*>(&Vt_lds[vrow * 72 + tcol + 8]) = vv1;       \
        __syncthreads();                                                      \
        _Pragma("unroll")                                                     \
        for (int ks = 0; ks < 2; ++ks) {                                      \
            const int colr_ = 32 * ks + 8 * (lg ^ (lm >> 2));                 \
            const bf8 ae_  = *reinterpret_cast<const bf8*>(                   \
                &E_lds [(16 * w + lm) * 72 + colr_]);                         \
            const bf8 aea_ = *reinterpret_cast<const bf8*>(                   \
                &Ea_lds[(16 * w + lm) * 72 + colr_]);                         \
            _Pragma("unroll")                                                 \
            for (int nf = 0; nf < 4; ++nf) {                                  \
                const bf8 bv_ = *reinterpret_cast<const bf8*>(                \
                    &Vt_lds[(lm + 16 * nf) * 72 + 32 * ks + 8 * lg]);         \
                acc1[nf] = __builtin_amdgcn_mfma_f32_16x16x32_bf16(ae_,  bv_, acc1[nf], 0, 0, 0); \
                acc2[nf] = __builtin_amdgcn_mfma_f32_16x16x32_bf16(aea_, bv_, acc2[nf], 0, 0, 0); \
            }                                                                 \
        }                                                                     \
    }

__global__ __launch_bounds__(256)
void k_pass2(const unsigned short* __restrict__ qb,
             const unsigned short* __restrict__ vT,
             const unsigned short* __restrict__ mvb,
             const float* __restrict__ a,
             const float* __restrict__ invn,
             unsigned short* __restrict__ ctxb,
             float* __restrict__ t2p)
{
    __shared__ unsigned short E_lds [64 * 72];
    __shared__ unsigned short Ea_lds[64 * 72];
    __shared__ unsigned short Vt_lds[64 * 72];
    __shared__ float red[256];
    const int st = blockIdx.x, bh = blockIdx.y;
    const int b = bh / 12, h = bh % 12;
    const int s0 = st * 64;
    const int tid = threadIdx.x;
    const int w = tid >> 6, lane = tid & 63, lm = lane & 15, lg = lane >> 4;
    const size_t qoff = (size_t)(b * 1024) * 768 + h * 64;
    const unsigned short* arow_p = qb + qoff + (size_t)(s0 + 16 * w + lm) * 768;
    const bf8 qa0 = ld8(arow_p + 8 * lg);
    const bf8 qa1 = ld8(arow_p + 32 + 8 * lg);
    const int vrow = tid >> 2;          // d 0..63
    const int tcol = (tid & 3) * 16;    // t-offset within chunk
    const unsigned short* vTbase = vT + (size_t)bh * 65536 + (size_t)vrow * 1024;
    const float* abase = a + (size_t)bh * 1024;
    float inv2[4];
    #pragma unroll
    for (int nf = 0; nf < 4; ++nf) {
        const float iv = invn[bh * 64 + lm + 16 * nf];
        inv2[nf] = iv * iv;
    }
    const f32x4 z = {0.f, 0.f, 0.f, 0.f};
    f32x4 acc1[4], acc2[4];
    #pragma unroll
    for (int nf = 0; nf < 4; ++nf) { acc1[nf] = z; acc2[nf] = z; }
    float gpart[4] = {0.f, 0.f, 0.f, 0.f};

    bf8 bA0[4], bA1[4], bB0[4], bB1[4];
    u16x8 vA0, vA1, vB0, vB1;
    float aA[4], aB[4];
    P2_LOAD(0, bA0, bA1, vA0, vA1, aA);
    for (int tt = 0; tt < 16; tt += 2) {
        P2_LOAD(tt + 1, bB0, bB1, vB0, vB1, aB);
        P2_COMP(bA0, bA1, vA0, vA1, aA);
        if (tt + 2 < 16) P2_LOAD(tt + 2, bA0, bA1, vA0, vA1, aA);
        P2_COMP(bB0, bB1, vB0, vB1, aB);
    }

    #pragma unroll
    for (int j = 0; j < 4; ++j)
        #pragma unroll
        for (int k = 1; k < 16; k <<= 1)
            gpart[j] += __shfl_xor(gpart[j], k);

    float t2 = 0.f;
    #pragma unroll
    for (int j = 0; j < 4; ++j) {
        const int srow = s0 + 16 * w + 4 * lg + j;
        const float arow = abase[srow];
        const float rdv = 1.f / (0.5f * (1.f + gpart[j]));
        const size_t rowoff = (size_t)(b * 1024 + srow) * 768 + h * 64;
        #pragma unroll
        for (int nf = 0; nf < 4; ++nf) {
            const int d = lm + 16 * nf;
            const float cf = 0.5f * (arow * acc1[nf][j] + acc2[nf][j]);
            ctxb[rowoff + d] = f2bf(cf);
            const float vv = bf2f(mvb[rowoff + d]);
            t2 = fmaf(vv * cf, inv2[nf] * rdv, t2);
        }
    }
    red[tid] = t2;
    __syncthreads();
    for (int k = 128; k >= 1; k >>= 1) {
        if (tid < k) red[tid] += red[tid + k];
        __syncthreads();
    }
    if (tid == 0) t2p[bh * 16 + st] = red[0];
}

// ---------------------------------------------------------------------------
// Orthogonality term via MFMA Gram from vT: sum (VtV - I)^2 per head
// ---------------------------------------------------------------------------
__global__ __launch_bounds__(256)
void k_reg(const unsigned short* __restrict__ vT, const float* __restrict__ invn,
           float* __restrict__ regp)
{
    const int bh = blockIdx.x;
    const int tid = threadIdx.x;
    const int w = tid >> 6, lane = tid & 63, lm = lane & 15, lg = lane >> 4;
    const unsigned short* base = vT + (size_t)bh * 65536;
    const unsigned short* arowp = base + (size_t)(16 * w + lm) * 1024;
    const f32x4 z = {0.f, 0.f, 0.f, 0.f};
    f32x4 acc[4];
    #pragma unroll
    for (int nf = 0; nf < 4; ++nf) acc[nf] = z;
    for (int kb = 0; kb < 32; ++kb) {
        const int t0 = kb * 32 + 8 * lg;
        const bf8 av = ld8(arowp + t0);
        #pragma unroll
        for (int nf = 0; nf < 4; ++nf) {
            const bf8 bv = ld8(base + (size_t)(lm + 16 * nf) * 1024 + t0);
            acc[nf] = __builtin_amdgcn_mfma_f32_16x16x32_bf16(av, bv, acc[nf], 0, 0, 0);
        }
    }
    float part = 0.f;
    #pragma unroll
    for (int nf = 0; nf < 4; ++nf) {
        const int d2 = lm + 16 * nf;
        const float i2 = invn[bh * 64 + d2];
        #pragma unroll
        for (int j = 0; j < 4; ++j) {
            const int d1 = 16 * w + 4 * lg + j;
            const float g = acc[nf][j] * invn[bh * 64 + d1] * i2;
            const float diff = g - ((d1 == d2) ? 1.f : 0.f);
            part = fmaf(diff, diff, part);
        }
    }
    __shared__ float red[256];
    red[tid] = part;
    __syncthreads();
    for (int k = 128; k >= 1; k >>= 1) {
        if (tid < k) red[tid] += red[tid + k];
        __syncthreads();
    }
    if (tid == 0) regp[bh] = red[0];
}

// ---------------------------------------------------------------------------
// Final deterministic reduction
// ---------------------------------------------------------------------------
__global__ __launch_bounds__(256)
void k_final(const float* __restrict__ t1p, const float* __restrict__ t2p,
             const float* __restrict__ regp, float* __restrict__ out_tr,
             float* __restrict__ out_reg)
{
    const int tid = threadIdx.x;
    float s1 = 0.f, s2 = 0.f, s3 = 0.f;
    for (int i = tid; i < 768; i += 256) s2 += t2p[i];
    if (tid < 48) { s1 = t1p[tid]; s3 = regp[tid]; }
    __shared__ float R1[256];
    __shared__ float R2[256];
    __shared__ float R3[256];
    R1[tid] = s1; R2[tid] = s2; R3[tid] = s3;
    __syncthreads();
    for (int w = 128; w >= 1; w >>= 1) {
        if (tid < w) { R1[tid] += R1[tid + w]; R2[tid] += R2[tid + w]; R3[tid] += R3[tid + w]; }
        __syncthreads();
    }
    if (tid == 0) {
        *out_tr  = fabsf(R1[0] - R2[0]) / 3072.f;
        *out_reg = R3[0] / 3072.f;
    }
}

// ---------------------------------------------------------------------------
extern "C" void kernel_launch(void* const* d_in, const int* in_sizes, int n_in,
                              void* d_out, int out_size, void* d_ws, size_t ws_size,
                              hipStream_t stream)
{
    const float* X  = (const float*)d_in[0];
    const float* Wq = (const float*)d_in[1];
    const float* bq = (const float*)d_in[2];
    const float* Wv = (const float*)d_in[3];
    const float* bv = (const float*)d_in[4];
    const float* Wo = (const float*)d_in[5];
    const float* bo = (const float*)d_in[6];

    float* out = (float*)d_out;
    float* att = out;                         // [4096,768]
    float* tr  = out + 3145728;
    float* rg  = out + 3145729;
    float* mq1 = out + 3145730;               // mixed_q (output 3)
    float* mq2 = out + 6291458;               // mixed_q (output 4)

    float* ws = (float*)d_ws;
    // Liveness-aliased layout (ws requirement unchanged at ~25.8 MB):
    unsigned short* mvb  = (unsigned short*)(ws);             // [4096,768] bf16
    unsigned short* qb   = (unsigned short*)(ws + 1572864);   // [4096,768] bf16
    // vT slot: WTq/WTv live until k_gemm_qv; vT until k_reg; then WTo.
    unsigned short* vTslot = (unsigned short*)(ws + 3145728); // 3.1M u16
    unsigned short* WTq  = vTslot;                            // [768,768] bf16
    unsigned short* WTv  = vTslot + 589824;
    unsigned short* vT   = vTslot;
    unsigned short* WTo  = vTslot;
    // Xb lives until k_gemm_qv; ctxb written by k_pass2 afterwards.
    unsigned short* Xb   = (unsigned short*)(ws + 4718592);   // [4096,768] bf16
    unsigned short* ctxb = (unsigned short*)(ws + 4718592);
    float* aarr = ws + 6389760;               // [48,1024]
    float* invn = ws + 6438960;               // [48,64]
    float* t1p  = ws + 6442032;               // [48]
    float* t2p  = ws + 6442080;               // [768]
    float* regp = ws + 6442848;               // [48]

    if (ws_size < (size_t)6442896 * sizeof(float)) return;

    k_xcast    <<<1536,         256, 0, stream>>>(X, Xb);
    k_wt       <<<dim3(12, 12), 256, 0, stream>>>(Wq, WTq);
    k_wt       <<<dim3(12, 12), 256, 0, stream>>>(Wv, WTv);
    k_gemm_qv  <<<dim3(32, 12), 256, 0, stream>>>(Xb, WTq, WTv, bq, bv, mq1, mq2, qb, mvb);
    k_colnorm  <<<48,           256, 0, stream>>>(mvb, invn, t1p);
    k_transpose<<<dim3(16, 48), 256, 0, stream>>>(mvb, vT);
    k_pass1    <<<dim3(16, 48), 256, 0, stream>>>(qb, aarr);
    k_pass2    <<<dim3(16, 48), 256, 0, stream>>>(qb, vT, mvb, aarr, invn, ctxb, t2p);
    k_reg      <<<48,           256, 0, stream>>>(vT, invn, regp);
    k_final    <<<1,            256, 0, stream>>>(t1p, t2p, regp, tr, rg);
    k_wt       <<<dim3(12, 12), 256, 0, stream>>>(Wo, WTo);
    k_gemm_one <<<dim3(32, 6),  256, 0, stream>>>(ctxb, WTo, bo, att);
}